// Round 9
// baseline (594.071 us; speedup 1.0000x reference)
//
#include <hip/hip_runtime.h>
#include <math.h>

#define NN 20000
#define EE 320000
#define NBINS 2048
#define HRANGE 64.0f
#define EPSF 1e-20f

typedef __attribute__((ext_vector_type(8))) short bf16x8;
typedef __attribute__((ext_vector_type(4))) float f32x4;

// ---------------- workspace layout (f32-slot offsets, all 16B-aligned) -----
constexpr size_t OFF_DEG  = 0;                    // NN ints
constexpr size_t OFF_RS   = 20000;                // NN+1 ints (+pad)
constexpr size_t OFF_CUR  = 40008;                // NN ints; after fill_csr
                                                  // this region is reused as PERM
constexpr size_t OFF_EIX  = 60008;                // EE ints
constexpr size_t OFF_GSRC = 380008;               // EE ints
constexpr size_t OFF_B0   = 700008;               // NN*128 bf16 (1280000 slots)
constexpr size_t OFF_B1   = 1980008;              // NN*128 bf16
constexpr size_t OFF_PA   = 3260008;              // NN*512 bf16
constexpr size_t OFF_PB   = 8380008;              // NN*512 bf16
constexpr size_t OFF_PE   = 13500008;             // EE f32 (CSR order)
constexpr size_t OFF_DL   = 13820008;             // EE f32; first 384 ints are
                                                  // the sort bins (hb) early on
constexpr size_t OFF_TT   = 14140008;             // EE f32 (CSR order)
constexpr size_t OFF_HIST = 14460008;             // 2*NBINS f32
constexpr size_t OFF_SCAL = 14464104;             // 32 f32
constexpr size_t OFF_REP  = 14464136;             // 128 f32
constexpr size_t OFF_WT   = 14464264;             // 278528 bf16
// WT sub-offsets (bf16 units):
constexpr size_t WT_ENC0 = 0;         // 128x64 (n-major)
constexpr size_t WT_ENC  = 8192;      // 4 x 128x128
constexpr size_t WT_CLS0 = 73728;     // 128x64
constexpr size_t WT_CLS  = 81920;     // 4 x 128x128
constexpr size_t WT_EA1  = 147456;    // 512x256

__device__ __forceinline__ unsigned ordf(float f) {
  unsigned b = __float_as_uint(f);
  return (b >> 31) ? ~b : (b | 0x80000000u);
}
__device__ __forceinline__ float unordf(unsigned u) {
  unsigned b = (u >> 31) ? (u ^ 0x80000000u) : ~u;
  return __uint_as_float(b);
}
__device__ __forceinline__ ushort f2bf(float f) {   // RNE
  unsigned u = __float_as_uint(f);
  u += 0x7FFFu + ((u >> 16) & 1u);
  return (ushort)(u >> 16);
}
__device__ __forceinline__ unsigned pack2(float x, float y) {
  return (unsigned)f2bf(x) | ((unsigned)f2bf(y) << 16);
}
__device__ __forceinline__ float bf2f(ushort h) {
  return __uint_as_float(((unsigned)h) << 16);
}
__device__ __forceinline__ float bflo(unsigned v) { return __uint_as_float(v << 16); }
__device__ __forceinline__ float bfhi(unsigned v) { return __uint_as_float(v & 0xFFFF0000u); }
// speculative-slot clamp: keep prefetch addresses inside the node's own edge
// range so overshoot re-reads the LAST row (L1/L2 hit) instead of fetching a
// random far row. Clamped slots are never accumulated (guarded) -> bit-exact.
// [round 7: -12.6us total]
__device__ __forceinline__ int eclamp(int j, int hi) {
  return max(min(j, hi), 0);
}

// ---------------- init ------------------------------------------------------
__global__ void init_ws(int* deg, int* cur, float* hist, float* scal, float* rep,
                        int* hb) {
  int i = blockIdx.x * blockDim.x + threadIdx.x;
  if (i < NN) { deg[i] = 0; cur[i] = 0; }
  if (i < 2 * NBINS) hist[i] = 0.f;
  if (i < 384) hb[i] = 0;
  if (i < 128) rep[i] = 0.f;
  if (i < 32) {
    if (i == 2)      ((unsigned*)scal)[2] = 0xFFFFFFFFu;
    else if (i == 3) ((unsigned*)scal)[3] = 0u;
    else scal[i] = 0.f;
  }
}

// ---------------- CSR build -------------------------------------------------
__global__ void count_deg(const int* __restrict__ dst, int* __restrict__ deg) {
  int e = blockIdx.x * 256 + threadIdx.x;
  if (e < EE) atomicAdd(&deg[dst[e]], 1);
}

__global__ __launch_bounds__(1024) void scan_deg(const int* __restrict__ deg,
                                                 int* __restrict__ rs) {
  __shared__ int ps[1024];
  const int t = threadIdx.x;
  const int base = t * 20;
  int loc[20];
  int s = 0;
#pragma unroll
  for (int j = 0; j < 20; ++j) {
    int idx = base + j;
    int v = (idx < NN) ? deg[idx] : 0;
    loc[j] = s;
    s += v;
  }
  ps[t] = s;
  __syncthreads();
  for (int off = 1; off < 1024; off <<= 1) {
    int x = (t >= off) ? ps[t - off] : 0;
    __syncthreads();
    ps[t] += x;
    __syncthreads();
  }
  const int excl = ps[t] - s;
#pragma unroll
  for (int j = 0; j < 20; ++j) {
    int idx = base + j;
    if (idx < NN) rs[idx] = excl + loc[j];
  }
  if (t == 1023) rs[NN] = ps[1023];
}

__global__ void fill_csr(const int* __restrict__ src, const int* __restrict__ dst,
                         const int* __restrict__ rs, int* __restrict__ cur,
                         int* __restrict__ eidx, int* __restrict__ gsrc) {
  int e = blockIdx.x * 256 + threadIdx.x;
  if (e < EE) {
    int d = dst[e];
    int p = atomicAdd(&cur[d], 1);
    int o = rs[d] + p;
    eidx[o] = e;
    gsrc[o] = src[e];
  }
}

// ---------------- degree-bucketed node permutation --------------------------
// Blocks process nodes via perm (deg-sorted). Rationale: a block's gather
// phase ends only when its slowest node finishes; E[max deg of 16 iid
// Poisson(16)] ~ 25 vs mean 16 -> ~1.55x straggler waste. Sorting makes
// per-block degrees uniform. Pure scheduling change: per-node computation,
// CSR indexing, and output rows unchanged -> bit-exact.
// hb layout: [0:128) histogram, [128:256) bucket base, [256:384) cursor.
__global__ void deg_hist(const int* __restrict__ deg, int* __restrict__ hb) {
  __shared__ int lb[128];
  if (threadIdx.x < 128) lb[threadIdx.x] = 0;
  __syncthreads();
  int i = blockIdx.x * 256 + threadIdx.x;
  if (i < NN) atomicAdd(&lb[min(deg[i], 127)], 1);
  __syncthreads();
  if (threadIdx.x < 128 && lb[threadIdx.x]) atomicAdd(&hb[threadIdx.x], lb[threadIdx.x]);
}

__global__ __launch_bounds__(128) void bucket_scan(int* __restrict__ hb) {
  __shared__ int ps[128];
  const int t = threadIdx.x;
  int v = hb[t];
  ps[t] = v;
  __syncthreads();
  for (int off = 1; off < 128; off <<= 1) {
    int x = (t >= off) ? ps[t - off] : 0;
    __syncthreads();
    ps[t] += x;
    __syncthreads();
  }
  hb[128 + t] = ps[t] - v;   // exclusive base
  hb[256 + t] = 0;           // cursor
}

__global__ void fill_perm(const int* __restrict__ deg, int* __restrict__ hb,
                          int* __restrict__ perm) {
  int n = blockIdx.x * 256 + threadIdx.x;
  if (n < NN) {
    int b = min(deg[n], 127);
    int p = atomicAdd(&hb[256 + b], 1);
    perm[hb[128 + b] + p] = n;
  }
}

// ---------------- all weight transposes in one kernel -----------------------
__global__ void transpose_all(const float* __restrict__ encW0, const float* __restrict__ encW,
                              const float* __restrict__ clsW0, const float* __restrict__ clsW,
                              const float* __restrict__ eaW1, ushort* __restrict__ Wt) {
  int i = blockIdx.x * 256 + threadIdx.x;
  if (i < 8192) {                       // enc_W0: 64x128 -> [n][k]
    int k = i >> 7, n = i & 127;
    Wt[WT_ENC0 + n * 64 + k] = f2bf(encW0[i]);
  } else if (i < 73728) {               // enc_W: 4 x 128x128
    int j = i - 8192;
    int l = j >> 14, r = j & 16383, k = r >> 7, n = r & 127;
    Wt[WT_ENC + l * 16384 + n * 128 + k] = f2bf(encW[j]);
  } else if (i < 81920) {               // cls_W0
    int j = i - 73728;
    int k = j >> 7, n = j & 127;
    Wt[WT_CLS0 + n * 64 + k] = f2bf(clsW0[j]);
  } else if (i < 147456) {              // cls_W
    int j = i - 81920;
    int l = j >> 14, r = j & 16383, k = r >> 7, n = r & 127;
    Wt[WT_CLS + l * 16384 + n * 128 + k] = f2bf(clsW[j]);
  } else if (i < 278528) {              // ea_W1: 256x512 -> [n][k]
    int j = i - 147456;
    int k = j >> 9, n = j & 511;
    Wt[WT_EA1 + n * 256 + k] = f2bf(eaW1[j]);
  }
}

// ---------------- fused GIN layer, K=64 (fp32 x in, bf16 out) ---------------
// v7 = v6 (16 nodes/block, 16 lanes/node, depth-4 pipeline, eclamp) with
// deg-sorted node order via perm. Output row = actual node id -> bit-exact.
template <bool HASATT>
__global__ __launch_bounds__(256) void fused_layer64(
    const float* __restrict__ X, ushort* __restrict__ C,
    const int* __restrict__ gsrc, const int* __restrict__ rs,
    const float* __restrict__ att, const ushort* __restrict__ Bt,
    const float* __restrict__ bias, const int* __restrict__ perm) {
  __shared__ __align__(16) char smem[8448];
  ushort* Asm = (ushort*)smem;                 // [16][72] bf16 (144B rows)
  const int tid = threadIdx.x;
  const int g = tid >> 4, l = tid & 15;
  const int nb = blockIdx.x * 16;
  {
    const int n = perm[nb + g];
    const int e0 = rs[n];
    const int deg = rs[n + 1] - e0;
    const int hi = e0 + deg - 1;
    float4 s = ((const float4*)(X + (size_t)n * 64))[l];
    float a[4] = {s.x, s.y, s.z, s.w};
    const float4* Xr = (const float4*)X;

    int i0 = gsrc[eclamp(e0 + 0, hi)];
    int i1 = gsrc[eclamp(e0 + 1, hi)];
    int i2 = gsrc[eclamp(e0 + 2, hi)];
    int i3 = gsrc[eclamp(e0 + 3, hi)];
    float4 F0 = Xr[(size_t)i0 * 16 + l];
    float4 F1 = Xr[(size_t)i1 * 16 + l];
    float4 F2 = Xr[(size_t)i2 * 16 + l];
    float4 F3 = Xr[(size_t)i3 * 16 + l];
    int G0 = gsrc[eclamp(e0 + 4, hi)];
    int G1 = gsrc[eclamp(e0 + 5, hi)];
    int G2 = gsrc[eclamp(e0 + 6, hi)];
    int G3 = gsrc[eclamp(e0 + 7, hi)];
    float W0 = 1.f, W1 = 1.f, W2 = 1.f, W3 = 1.f;
    if (HASATT) {
      W0 = att[eclamp(e0 + 0, hi)];
      W1 = att[eclamp(e0 + 1, hi)];
      W2 = att[eclamp(e0 + 2, hi)];
      W3 = att[eclamp(e0 + 3, hi)];
    }

#define FL64_STEP(F, G, W, J)                                                 \
    {                                                                         \
      if ((J) < deg) {                                                        \
        const float cw_ = HASATT ? (W) : 1.f;                                 \
        a[0] = fmaf(cw_, F.x, a[0]); a[1] = fmaf(cw_, F.y, a[1]);             \
        a[2] = fmaf(cw_, F.z, a[2]); a[3] = fmaf(cw_, F.w, a[3]);             \
      }                                                                       \
      F = Xr[(size_t)G * 16 + l];                                             \
      G = gsrc[eclamp(e0 + (J) + 8, hi)];                                     \
      if (HASATT) W = att[eclamp(e0 + (J) + 4, hi)];                          \
    }

    for (int j = 0; j < deg; j += 4) {
      FL64_STEP(F0, G0, W0, j);
      FL64_STEP(F1, G1, W1, j + 1);
      FL64_STEP(F2, G2, W2, j + 2);
      FL64_STEP(F3, G3, W3, j + 3);
    }
#undef FL64_STEP
    ushort4 o;
    o.x = f2bf(a[0]); o.y = f2bf(a[1]); o.z = f2bf(a[2]); o.w = f2bf(a[3]);
    *(ushort4*)(Asm + g * 72 + l * 4) = o;
  }
  __syncthreads();
  const int wave = tid >> 6, lane = tid & 63, quad = lane >> 4, l15 = lane & 15;
  f32x4 acc[2] = {{0.f, 0.f, 0.f, 0.f}, {0.f, 0.f, 0.f, 0.f}};
#pragma unroll
  for (int k0 = 0; k0 < 64; k0 += 32) {
    bf16x8 af = *(const bf16x8*)(Asm + l15 * 72 + k0 + quad * 8);
#pragma unroll
    for (int t = 0; t < 2; ++t) {
      int bn = wave * 32 + t * 16 + l15;
      bf16x8 bf = *(const bf16x8*)(Bt + (size_t)bn * 64 + k0 + quad * 8);
      acc[t] = __builtin_amdgcn_mfma_f32_16x16x32_bf16(af, bf, acc[t], 0, 0, 0);
    }
  }
  __syncthreads();
  float (*Csm)[132] = (float(*)[132])smem;
#pragma unroll
  for (int t = 0; t < 2; ++t) {
    int lc = wave * 32 + t * 16 + l15;
    float bs = bias[lc];
#pragma unroll
    for (int r = 0; r < 4; ++r)
      Csm[quad * 4 + r][lc] = fmaxf(acc[t][r] + bs, 0.f);
  }
  __syncthreads();
  const int r = tid >> 4, cc = (tid & 15) * 8;
  const int pn = perm[nb + r];
  f32x4 v0 = *(const f32x4*)&Csm[r][cc];
  f32x4 v1 = *(const f32x4*)&Csm[r][cc + 4];
  uint4 o;
  o.x = pack2(v0[0], v0[1]); o.y = pack2(v0[2], v0[3]);
  o.z = pack2(v1[0], v1[1]); o.w = pack2(v1[2], v1[3]);
  *(uint4*)(C + (size_t)pn * 128 + cc) = o;
}

// ---------------- fused GIN layer, K=128 (bf16 in/out) ----------------------
// v7 = v6 with deg-sorted node order via perm. Row = 128 bf16 = 16 uint4.
template <bool HASATT>
__global__ __launch_bounds__(256) void fused_layer128(
    const ushort* __restrict__ Xb, ushort* __restrict__ C,
    const int* __restrict__ gsrc, const int* __restrict__ rs,
    const float* __restrict__ att, const ushort* __restrict__ Bt,
    const float* __restrict__ bias, const int* __restrict__ perm) {
  __shared__ __align__(16) char smem[8448];
  ushort* Asm = (ushort*)smem;                 // [16][136] bf16 (272B rows)
  const int tid = threadIdx.x;
  const int g = tid >> 4, l = tid & 15;
  const int nb = blockIdx.x * 16;
  {
    const int n = perm[nb + g];
    const int e0 = rs[n];
    const int deg = rs[n + 1] - e0;
    const int hi = e0 + deg - 1;
    float a[8];
    {
      uint4 s = ((const uint4*)(Xb + (size_t)n * 128))[l];
      a[0] = bflo(s.x); a[1] = bfhi(s.x); a[2] = bflo(s.y); a[3] = bfhi(s.y);
      a[4] = bflo(s.z); a[5] = bfhi(s.z); a[6] = bflo(s.w); a[7] = bfhi(s.w);
    }
    const uint4* Xr = (const uint4*)Xb;

    int i0 = gsrc[eclamp(e0 + 0, hi)];
    int i1 = gsrc[eclamp(e0 + 1, hi)];
    int i2 = gsrc[eclamp(e0 + 2, hi)];
    int i3 = gsrc[eclamp(e0 + 3, hi)];
    uint4 F0 = Xr[(size_t)i0 * 16 + l];
    uint4 F1 = Xr[(size_t)i1 * 16 + l];
    uint4 F2 = Xr[(size_t)i2 * 16 + l];
    uint4 F3 = Xr[(size_t)i3 * 16 + l];
    int G0 = gsrc[eclamp(e0 + 4, hi)];
    int G1 = gsrc[eclamp(e0 + 5, hi)];
    int G2 = gsrc[eclamp(e0 + 6, hi)];
    int G3 = gsrc[eclamp(e0 + 7, hi)];
    float W0 = 1.f, W1 = 1.f, W2 = 1.f, W3 = 1.f;
    if (HASATT) {
      W0 = att[eclamp(e0 + 0, hi)];
      W1 = att[eclamp(e0 + 1, hi)];
      W2 = att[eclamp(e0 + 2, hi)];
      W3 = att[eclamp(e0 + 3, hi)];
    }

#define FL128_STEP(F, G, W, J)                                                \
    {                                                                         \
      if ((J) < deg) {                                                        \
        const float cw_ = HASATT ? (W) : 1.f;                                 \
        a[0] = fmaf(cw_, bflo(F.x), a[0]); a[1] = fmaf(cw_, bfhi(F.x), a[1]); \
        a[2] = fmaf(cw_, bflo(F.y), a[2]); a[3] = fmaf(cw_, bfhi(F.y), a[3]); \
        a[4] = fmaf(cw_, bflo(F.z), a[4]); a[5] = fmaf(cw_, bfhi(F.z), a[5]); \
        a[6] = fmaf(cw_, bflo(F.w), a[6]); a[7] = fmaf(cw_, bfhi(F.w), a[7]); \
      }                                                                       \
      F = Xr[(size_t)G * 16 + l];                                             \
      G = gsrc[eclamp(e0 + (J) + 8, hi)];                                     \
      if (HASATT) W = att[eclamp(e0 + (J) + 4, hi)];                          \
    }

    for (int j = 0; j < deg; j += 4) {
      FL128_STEP(F0, G0, W0, j);
      FL128_STEP(F1, G1, W1, j + 1);
      FL128_STEP(F2, G2, W2, j + 2);
      FL128_STEP(F3, G3, W3, j + 3);
    }
#undef FL128_STEP
    uint4 o;
    o.x = pack2(a[0], a[1]); o.y = pack2(a[2], a[3]);
    o.z = pack2(a[4], a[5]); o.w = pack2(a[6], a[7]);
    *(uint4*)(Asm + g * 136 + l * 8) = o;
  }
  __syncthreads();
  const int wave = tid >> 6, lane = tid & 63, quad = lane >> 4, l15 = lane & 15;
  f32x4 acc[2] = {{0.f, 0.f, 0.f, 0.f}, {0.f, 0.f, 0.f, 0.f}};
#pragma unroll
  for (int k0 = 0; k0 < 128; k0 += 32) {
    bf16x8 af = *(const bf16x8*)(Asm + l15 * 136 + k0 + quad * 8);
#pragma unroll
    for (int t = 0; t < 2; ++t) {
      int bn = wave * 32 + t * 16 + l15;
      bf16x8 bf = *(const bf16x8*)(Bt + (size_t)bn * 128 + k0 + quad * 8);
      acc[t] = __builtin_amdgcn_mfma_f32_16x16x32_bf16(af, bf, acc[t], 0, 0, 0);
    }
  }
  __syncthreads();
  float (*Csm)[132] = (float(*)[132])smem;
#pragma unroll
  for (int t = 0; t < 2; ++t) {
    int lc = wave * 32 + t * 16 + l15;
    float bs = bias[lc];
#pragma unroll
    for (int r = 0; r < 4; ++r)
      Csm[quad * 4 + r][lc] = fmaxf(acc[t][r] + bs, 0.f);
  }
  __syncthreads();
  const int r = tid >> 4, cc = (tid & 15) * 8;
  const int pn = perm[nb + r];
  f32x4 v0 = *(const f32x4*)&Csm[r][cc];
  f32x4 v1 = *(const f32x4*)&Csm[r][cc + 4];
  uint4 o;
  o.x = pack2(v0[0], v0[1]); o.y = pack2(v0[2], v0[3]);
  o.z = pack2(v1[0], v1[1]); o.w = pack2(v1[2], v1[3]);
  *(uint4*)(C + (size_t)pn * 128 + cc) = o;
}

// ---------------- Pa+Pb fused: grid (4, 625) --------------------------------
// One block computes its 32x128 tile for BOTH Pa and Pb (round 8: FETCH
// halved as predicted but time 55.5->51.5 only — floor mechanism still
// unidentified; left unchanged this round).
__global__ __launch_bounds__(256) void gemm_papb(
    const ushort* __restrict__ Hb, const ushort* __restrict__ W1t,
    const float* __restrict__ b1, ushort* __restrict__ Pa, ushort* __restrict__ Pb) {
  __shared__ float lds[32][132];
  const int tid = threadIdx.x;
  const int wave = tid >> 6, lane = tid & 63, quad = lane >> 4, l15 = lane & 15;
  const int mh = wave >> 1, nh = wave & 1;
  const int col0 = blockIdx.x * 128;
  const int row0 = blockIdx.y * 32;
  f32x4 accA[4] = {{0.f, 0.f, 0.f, 0.f}, {0.f, 0.f, 0.f, 0.f},
                   {0.f, 0.f, 0.f, 0.f}, {0.f, 0.f, 0.f, 0.f}};
  f32x4 accB[4] = {{0.f, 0.f, 0.f, 0.f}, {0.f, 0.f, 0.f, 0.f},
                   {0.f, 0.f, 0.f, 0.f}, {0.f, 0.f, 0.f, 0.f}};
  const ushort* Ap = Hb + (size_t)(row0 + mh * 16 + l15) * 128 + quad * 8;
#pragma unroll
  for (int k0 = 0; k0 < 128; k0 += 32) {
    bf16x8 af = *(const bf16x8*)(Ap + k0);
#pragma unroll
    for (int t = 0; t < 4; ++t) {
      int bn = col0 + nh * 64 + t * 16 + l15;
      const ushort* Brow = W1t + (size_t)bn * 256 + k0 + quad * 8;
      bf16x8 bfa = *(const bf16x8*)(Brow);
      bf16x8 bfb = *(const bf16x8*)(Brow + 128);
      accA[t] = __builtin_amdgcn_mfma_f32_16x16x32_bf16(af, bfa, accA[t], 0, 0, 0);
      accB[t] = __builtin_amdgcn_mfma_f32_16x16x32_bf16(af, bfb, accB[t], 0, 0, 0);
    }
  }
#pragma unroll
  for (int pass = 0; pass < 2; ++pass) {
    if (pass) __syncthreads();          // previous pass's readers done
#pragma unroll
    for (int t = 0; t < 4; ++t) {
      int lc = nh * 64 + t * 16 + l15;
      float bs = pass ? 0.f : b1[col0 + lc];
      f32x4 av = pass ? accB[t] : accA[t];
#pragma unroll
      for (int r = 0; r < 4; ++r)
        lds[mh * 16 + quad * 4 + r][lc] = av[r] + bs;
    }
    __syncthreads();
    ushort* C = pass ? Pb : Pa;
    const int r = tid >> 3, c0 = (tid & 7) * 16;
    ushort* Cp = C + (size_t)(row0 + r) * 512 + col0 + c0;
#pragma unroll
    for (int k = 0; k < 4; ++k) {
      f32x4 v = *(const f32x4*)&lds[r][c0 + k * 4];
      ushort4 o;
      o.x = f2bf(v[0]); o.y = f2bf(v[1]); o.z = f2bf(v[2]); o.w = f2bf(v[3]);
      *(ushort4*)(Cp + k * 4) = o;
    }
  }
}

// ---------------- edge MLP layer 2: one full wave per dst node --------------
// v7 = v6 (pipelined wave-per-node, coalesced rows, butterfly, eclamp) with
// deg-sorted node order via perm (max-of-4 straggler -> uniform).
__global__ __launch_bounds__(256) void edge_pe_csr(
    const ushort* __restrict__ Pa, const ushort* __restrict__ Pb,
    const int* __restrict__ gsrc, const int* __restrict__ rs,
    const float* __restrict__ W2, const float* __restrict__ b2,
    float* __restrict__ pe, const int* __restrict__ perm) {
  const int lane = threadIdx.x & 63;
  const int n = perm[blockIdx.x * 4 + (threadIdx.x >> 6)];
  const int e0 = rs[n];
  const int deg = rs[n + 1] - e0;
  if (deg <= 0) return;
  const int hi = e0 + deg - 1;
  float w[8], pb[8];
  {
    const float4* w2v = (const float4*)(W2 + lane * 8);
    float4 t0 = w2v[0], t1 = w2v[1];
    w[0] = t0.x; w[1] = t0.y; w[2] = t0.z; w[3] = t0.w;
    w[4] = t1.x; w[5] = t1.y; w[6] = t1.z; w[7] = t1.w;
    uint4 b = ((const uint4*)(Pb + (size_t)n * 512))[lane];
    pb[0] = bflo(b.x); pb[1] = bfhi(b.x); pb[2] = bflo(b.y); pb[3] = bfhi(b.y);
    pb[4] = bflo(b.z); pb[5] = bfhi(b.z); pb[6] = bflo(b.w); pb[7] = bfhi(b.w);
  }
  const float b2v = b2[0];
  const uint4* Par = (const uint4*)Pa;

  int i0 = gsrc[eclamp(e0 + 0, hi)];
  int i1 = gsrc[eclamp(e0 + 1, hi)];
  int i2 = gsrc[eclamp(e0 + 2, hi)];
  int i3 = gsrc[eclamp(e0 + 3, hi)];
  uint4 F0 = Par[(size_t)i0 * 64 + lane];
  uint4 F1 = Par[(size_t)i1 * 64 + lane];
  uint4 F2 = Par[(size_t)i2 * 64 + lane];
  uint4 F3 = Par[(size_t)i3 * 64 + lane];
  int G0 = gsrc[eclamp(e0 + 4, hi)];
  int G1 = gsrc[eclamp(e0 + 5, hi)];
  int G2 = gsrc[eclamp(e0 + 6, hi)];
  int G3 = gsrc[eclamp(e0 + 7, hi)];

#define PE_STEP(F, G, J)                                                      \
  {                                                                           \
    if ((J) < deg) {                                                          \
      float pa[8] = {bflo(F.x), bfhi(F.x), bflo(F.y), bfhi(F.y),              \
                     bflo(F.z), bfhi(F.z), bflo(F.w), bfhi(F.w)};             \
      float acc = 0.f;                                                        \
      _Pragma("unroll")                                                       \
      for (int jj = 0; jj < 8; ++jj) acc += fmaxf(pa[jj] + pb[jj], 0.f) * w[jj]; \
      _Pragma("unroll")                                                       \
      for (int off = 32; off; off >>= 1) acc += __shfl_xor(acc, off);         \
      if (lane == 0) pe[e0 + (J)] = acc + b2v;                                \
    }                                                                         \
    F = Par[(size_t)G * 64 + lane];                                           \
    G = gsrc[eclamp(e0 + (J) + 8, hi)];                                       \
  }

  for (int j = 0; j < deg; j += 4) {
    PE_STEP(F0, G0, j);
    PE_STEP(F1, G1, j + 1);
    PE_STEP(F2, G2, j + 2);
    PE_STEP(F3, G3, j + 3);
  }
#undef PE_STEP
}

// ---------------- pe statistics (sum, sumsq, min, max) ----------------------
__global__ __launch_bounds__(256) void pe_stats(const float* __restrict__ pe,
                                                float* __restrict__ scal) {
  __shared__ float r1[256], r2[256], r3[256], r4[256];
  int tid = threadIdx.x;
  float s = 0.f, q = 0.f, mn = 3.0e38f, mx = -3.0e38f;
  for (int i = blockIdx.x * 256 + tid; i < EE; i += gridDim.x * 256) {
    float v = pe[i];
    s += v; q = fmaf(v, v, q);
    mn = fminf(mn, v); mx = fmaxf(mx, v);
  }
  r1[tid] = s; r2[tid] = q; r3[tid] = mn; r4[tid] = mx;
  __syncthreads();
  for (int k = 128; k > 0; k >>= 1) {
    if (tid < k) {
      r1[tid] += r1[tid + k];
      r2[tid] += r2[tid + k];
      r3[tid] = fminf(r3[tid], r3[tid + k]);
      r4[tid] = fmaxf(r4[tid], r4[tid + k]);
    }
    __syncthreads();
  }
  if (tid == 0) {
    unsafeAtomicAdd(&scal[0], r1[0]);
    unsafeAtomicAdd(&scal[1], r2[0]);
    atomicMin((unsigned*)scal + 2, ordf(r3[0]));
    atomicMax((unsigned*)scal + 3, ordf(r4[0]));
  }
}

// ---------------- delta + histogram (CSR order; u gathered via eidx) --------
__global__ __launch_bounds__(256) void edge_delta_hist(
    const float* __restrict__ pe, const float* __restrict__ u,
    const int* __restrict__ eidx, float* __restrict__ delta,
    float* __restrict__ hist, const float* __restrict__ scal) {
  __shared__ float cnt_s[NBINS], sum_s[NBINS];
  for (int b = threadIdx.x; b < NBINS; b += 256) { cnt_s[b] = 0.f; sum_s[b] = 0.f; }
  float sum = scal[0], ssq = scal[1];
  float mn = unordf(((const unsigned*)scal)[2]);
  float mx = unordf(((const unsigned*)scal)[3]);
  float mu = sum / (float)EE;
  float var = (ssq - sum * sum / (float)EE) / (float)(EE - 1);
  float istd = rsqrtf(fmaxf(var, 1e-30f));
  float shift = (mn - mu) * istd + (mx - mu) * istd;
  __syncthreads();
  for (int i = blockIdx.x * 256 + threadIdx.x; i < EE; i += gridDim.x * 256) {
    float uu = u[eidx[i]];
    float atts = (pe[i] - mu) * istd;
    float g = -logf(-logf(uu + EPSF) + EPSF);
    float dl = 2.0f * (atts + g) - shift;
    delta[i] = dl;
    float dcl = fminf(fmaxf(dl, -HRANGE), HRANGE * 0.9999f);
    int b = (int)((dcl + HRANGE) * ((float)NBINS / (2.0f * HRANGE)));
    b = min(max(b, 0), NBINS - 1);
    atomicAdd(&cnt_s[b], 1.0f);
    atomicAdd(&sum_s[b], dcl);
  }
  __syncthreads();
  for (int b = threadIdx.x; b < NBINS; b += 256) {
    float c = cnt_s[b];
    if (c != 0.f) {
      unsafeAtomicAdd(&hist[b], c);
      unsafeAtomicAdd(&hist[NBINS + b], sum_s[b]);
    }
  }
}

// ---------------- scalar Sinkhorn recursion (single wave) -------------------
__global__ __launch_bounds__(64) void sinkhorn_iter(const float* __restrict__ hist,
                                                    float* __restrict__ scal) {
  const int lane = threadIdx.x;
  float cnt[32], mean[32];
#pragma unroll
  for (int b = 0; b < 32; ++b) {
    int idx = b * 64 + lane;
    float c = hist[idx];
    cnt[b] = c;
    mean[b] = (c > 0.f) ? hist[NBINS + idx] / c : 0.f;
  }
  const float LRD = -1.0986122886681098f;
  float S = 0.f, Zfin = 0.f;
  for (int it = 0; it < 30; ++it) {
    float p = 0.f;
#pragma unroll
    for (int b = 0; b < 32; ++b)
      if (cnt[b] > 0.f) p += cnt[b] / (1.f + expf(-(mean[b] + S)));
#pragma unroll
    for (int off = 32; off; off >>= 1) p += __shfl_xor(p, off);
    if (it < 29)
      S += logf(fmaxf((float)EE - p, 1.0f)) - logf(p) + LRD;
    else
      Zfin = p;
  }
  if (lane == 0) {
    scal[8] = S;
    scal[9] = ((float)EE * 0.25f) / Zfin;
  }
}

// ---------------- T_i (CSR order) -------------------------------------------
__global__ void compute_T(const float* __restrict__ delta,
                          const float* __restrict__ scal,
                          float* __restrict__ Ta) {
  int i = blockIdx.x * 256 + threadIdx.x;
  if (i >= EE) return;
  float S = scal[8], sc = scal[9];
  Ta[i] = sc / (1.f + expf(-(delta[i] + S)));
}

// ---------------- mean pooling (4 independent partials) + head --------------
__global__ __launch_bounds__(128) void col_mean(const ushort* __restrict__ Hc,
                                                float* __restrict__ rep) {
  int c = threadIdx.x;
  const int g = gridDim.x;
  float p0 = 0.f, p1 = 0.f, p2 = 0.f, p3 = 0.f;
  int n = blockIdx.x;
  for (; n + 3 * g < NN; n += 4 * g) {
    p0 += bf2f(Hc[(size_t)n * 128 + c]);
    p1 += bf2f(Hc[(size_t)(n + g) * 128 + c]);
    p2 += bf2f(Hc[(size_t)(n + 2 * g) * 128 + c]);
    p3 += bf2f(Hc[(size_t)(n + 3 * g) * 128 + c]);
  }
  for (; n < NN; n += g) p0 += bf2f(Hc[(size_t)n * 128 + c]);
  unsafeAtomicAdd(&rep[c], (p0 + p1) + (p2 + p3));
}

__global__ __launch_bounds__(128) void head_kernel(const float* __restrict__ repsum,
                                                   const float* __restrict__ hW,
                                                   const float* __restrict__ hb,
                                                   float* __restrict__ out) {
  __shared__ float rep[128];
  int tid = threadIdx.x;
  if (tid < 128) rep[tid] = repsum[tid] * (1.0f / (float)NN);
  __syncthreads();
  if (tid < 10) {
    float a = hb[tid];
#pragma unroll
    for (int c = 0; c < 128; c++) a = fmaf(rep[c], hW[c * 10 + tid], a);
    out[tid] = a;
  }
}

// ---------------- launch ----------------------------------------------------
extern "C" void kernel_launch(void* const* d_in, const int* in_sizes, int n_in,
                              void* d_out, int out_size, void* d_ws, size_t ws_size,
                              hipStream_t stream) {
  const float* x      = (const float*)d_in[0];
  const int*   ei     = (const int*)d_in[1];
  const float* u      = (const float*)d_in[2];
  const float* enc_W0 = (const float*)d_in[3];
  const float* enc_b0 = (const float*)d_in[4];
  const float* enc_W  = (const float*)d_in[5];
  const float* enc_b  = (const float*)d_in[6];
  const float* ea_W1  = (const float*)d_in[7];
  const float* ea_b1  = (const float*)d_in[8];
  const float* ea_W2  = (const float*)d_in[9];
  const float* ea_b2  = (const float*)d_in[10];
  const float* cls_W0 = (const float*)d_in[11];
  const float* cls_b0 = (const float*)d_in[12];
  const float* cls_W  = (const float*)d_in[13];
  const float* cls_b  = (const float*)d_in[14];
  const float* head_W = (const float*)d_in[15];
  const float* head_b = (const float*)d_in[16];
  const int* src  = ei;
  const int* dstp = ei + EE;

  float* wsF = (float*)d_ws;
  int*   wsI = (int*)d_ws;
  int* deg  = wsI + OFF_DEG;
  int* rs   = wsI + OFF_RS;
  int* cur  = wsI + OFF_CUR;
  int* perm = wsI + OFF_CUR;          // reuses cur AFTER fill_csr completes
  int* hb   = wsI + OFF_DL;           // sort bins; dl overwritten much later
  int* eix  = wsI + OFF_EIX;
  int* gsrc = wsI + OFF_GSRC;
  ushort* B0 = (ushort*)(wsF + OFF_B0);
  ushort* B1 = (ushort*)(wsF + OFF_B1);
  ushort* Pa = (ushort*)(wsF + OFF_PA);
  ushort* Pb = (ushort*)(wsF + OFF_PB);
  float* pe   = wsF + OFF_PE;
  float* dl   = wsF + OFF_DL;
  float* Ta   = wsF + OFF_TT;
  float* hist = wsF + OFF_HIST;
  float* scal = wsF + OFF_SCAL;
  float* rep  = wsF + OFF_REP;
  ushort* Wt  = (ushort*)(wsF + OFF_WT);
  float* out = (float*)d_out;

  init_ws<<<(NN + 255) / 256, 256, 0, stream>>>(deg, cur, hist, scal, rep, hb);
  count_deg<<<(EE + 255) / 256, 256, 0, stream>>>(dstp, deg);
  scan_deg<<<1, 1024, 0, stream>>>(deg, rs);
  fill_csr<<<(EE + 255) / 256, 256, 0, stream>>>(src, dstp, rs, cur, eix, gsrc);
  // deg-bucketed permutation (perm aliases cur -> must follow fill_csr)
  deg_hist<<<(NN + 255) / 256, 256, 0, stream>>>(deg, hb);
  bucket_scan<<<1, 128, 0, stream>>>(hb);
  fill_perm<<<(NN + 255) / 256, 256, 0, stream>>>(deg, hb, perm);
  transpose_all<<<1088, 256, 0, stream>>>(enc_W0, enc_W, cls_W0, cls_W, ea_W1, Wt);

  const int GB = NN / 16;  // 1250 (16 nodes per block)

  // encoder GIN stack (att = 1)
  fused_layer64<false><<<GB, 256, 0, stream>>>(x, B0, gsrc, rs, nullptr,
                                               Wt + WT_ENC0, enc_b0, perm);
  {
    ushort* in = B0; ushort* outb = B1;
    for (int l = 0; l < 4; l++) {
      fused_layer128<false><<<GB, 256, 0, stream>>>(in, outb, gsrc, rs, nullptr,
                                                    Wt + WT_ENC + (size_t)l * 16384,
                                                    enc_b + (size_t)l * 128, perm);
      ushort* t = in; in = outb; outb = t;
    }
  }
  // encoder output in B0

  gemm_papb<<<dim3(4, NN / 32), 256, 0, stream>>>(B0, Wt + WT_EA1, ea_b1, Pa, Pb);
  edge_pe_csr<<<NN / 4, 256, 0, stream>>>(Pa, Pb, gsrc, rs, ea_W2, ea_b2, pe, perm);

  pe_stats<<<512, 256, 0, stream>>>(pe, scal);
  edge_delta_hist<<<128, 256, 0, stream>>>(pe, u, eix, dl, hist, scal);
  sinkhorn_iter<<<1, 64, 0, stream>>>(hist, scal);
  compute_T<<<(EE + 255) / 256, 256, 0, stream>>>(dl, scal, Ta);

  // classifier GIN stack (att = T, CSR-ordered)
  fused_layer64<true><<<GB, 256, 0, stream>>>(x, B0, gsrc, rs, Ta,
                                              Wt + WT_CLS0, cls_b0, perm);
  {
    ushort* in = B0; ushort* outb = B1;
    for (int l = 0; l < 4; l++) {
      fused_layer128<true><<<GB, 256, 0, stream>>>(in, outb, gsrc, rs, Ta,
                                                   Wt + WT_CLS + (size_t)l * 16384,
                                                   cls_b + (size_t)l * 128, perm);
      ushort* t = in; in = outb; outb = t;
    }
  }

  col_mean<<<256, 128, 0, stream>>>(B0, rep);
  head_kernel<<<1, 128, 0, stream>>>(rep, head_W, head_b, out);
}

// Round 12
// 520.755 us; speedup vs baseline: 1.1408x; 1.1408x over previous
//
#include <hip/hip_runtime.h>
#include <math.h>

#define NN 20000
#define EE 320000
#define NBINS 2048
#define HRANGE 64.0f
#define EPSF 1e-20f

typedef __attribute__((ext_vector_type(8))) short bf16x8;
typedef __attribute__((ext_vector_type(4))) float f32x4;

// ---------------- workspace layout (f32-slot offsets, all 16B-aligned) -----
constexpr size_t OFF_DEG  = 0;                    // NN ints
constexpr size_t OFF_RS   = 20000;                // NN+1 ints (+pad)
constexpr size_t OFF_CUR  = 40008;                // NN ints
constexpr size_t OFF_EIX  = 60008;                // EE ints
constexpr size_t OFF_GSRC = 380008;               // EE ints
constexpr size_t OFF_B0   = 700008;               // NN*128 bf16 (1280000 slots)
constexpr size_t OFF_B1   = 1980008;              // NN*128 bf16
constexpr size_t OFF_PA   = 3260008;              // NN*512 bf16
constexpr size_t OFF_PB   = 8380008;              // NN*512 bf16
constexpr size_t OFF_PE   = 13500008;             // EE f32 (CSR order)
constexpr size_t OFF_DL   = 13820008;             // EE f32 (CSR order)
constexpr size_t OFF_TT   = 14140008;             // EE f32 (CSR order)
constexpr size_t OFF_HIST = 14460008;             // 2*NBINS f32
constexpr size_t OFF_SCAL = 14464104;             // 32 f32
constexpr size_t OFF_REP  = 14464136;             // 128 f32
constexpr size_t OFF_WT   = 14464264;             // 278528 bf16
// WT sub-offsets (bf16 units):
constexpr size_t WT_ENC0 = 0;         // 128x64 (n-major)
constexpr size_t WT_ENC  = 8192;      // 4 x 128x128
constexpr size_t WT_CLS0 = 73728;     // 128x64
constexpr size_t WT_CLS  = 81920;     // 4 x 128x128
constexpr size_t WT_EA1  = 147456;    // 512x256

__device__ __forceinline__ unsigned ordf(float f) {
  unsigned b = __float_as_uint(f);
  return (b >> 31) ? ~b : (b | 0x80000000u);
}
__device__ __forceinline__ float unordf(unsigned u) {
  unsigned b = (u >> 31) ? (u ^ 0x80000000u) : ~u;
  return __uint_as_float(b);
}
__device__ __forceinline__ ushort f2bf(float f) {   // RNE
  unsigned u = __float_as_uint(f);
  u += 0x7FFFu + ((u >> 16) & 1u);
  return (ushort)(u >> 16);
}
__device__ __forceinline__ unsigned pack2(float x, float y) {
  return (unsigned)f2bf(x) | ((unsigned)f2bf(y) << 16);
}
__device__ __forceinline__ float bf2f(ushort h) {
  return __uint_as_float(((unsigned)h) << 16);
}
__device__ __forceinline__ float bflo(unsigned v) { return __uint_as_float(v << 16); }
__device__ __forceinline__ float bfhi(unsigned v) { return __uint_as_float(v & 0xFFFF0000u); }
// speculative-slot clamp: keep prefetch addresses inside the node's own edge
// range so overshoot re-reads the LAST row (L1/L2 hit) instead of fetching a
// random far row. Clamped slots are never accumulated (guarded) -> bit-exact.
// [round 7: -12.6us total, edge_pe FETCH waste removed]
// NOTE (round 10): fp8-e4m3 Pa storage FAILED correctness (absmax 92) —
// Pa magnitudes exceed fp8's ±448 range (activation norms grow through the
// 5-layer GIN stack). Unscaled low-precision storage for H/Pa is not viable.
__device__ __forceinline__ int eclamp(int j, int hi) {
  return max(min(j, hi), 0);
}

// ---------------- init ------------------------------------------------------
__global__ void init_ws(int* deg, int* cur, float* hist, float* scal, float* rep) {
  int i = blockIdx.x * blockDim.x + threadIdx.x;
  if (i < NN) { deg[i] = 0; cur[i] = 0; }
  if (i < 2 * NBINS) hist[i] = 0.f;
  if (i < 128) rep[i] = 0.f;
  if (i < 32) {
    if (i == 2)      ((unsigned*)scal)[2] = 0xFFFFFFFFu;
    else if (i == 3) ((unsigned*)scal)[3] = 0u;
    else scal[i] = 0.f;
  }
}

// ---------------- CSR build -------------------------------------------------
__global__ void count_deg(const int* __restrict__ dst, int* __restrict__ deg) {
  int e = blockIdx.x * 256 + threadIdx.x;
  if (e < EE) atomicAdd(&deg[dst[e]], 1);
}

__global__ __launch_bounds__(1024) void scan_deg(const int* __restrict__ deg,
                                                 int* __restrict__ rs) {
  __shared__ int ps[1024];
  const int t = threadIdx.x;
  const int base = t * 20;
  int loc[20];
  int s = 0;
#pragma unroll
  for (int j = 0; j < 20; ++j) {
    int idx = base + j;
    int v = (idx < NN) ? deg[idx] : 0;
    loc[j] = s;
    s += v;
  }
  ps[t] = s;
  __syncthreads();
  for (int off = 1; off < 1024; off <<= 1) {
    int x = (t >= off) ? ps[t - off] : 0;
    __syncthreads();
    ps[t] += x;
    __syncthreads();
  }
  const int excl = ps[t] - s;
#pragma unroll
  for (int j = 0; j < 20; ++j) {
    int idx = base + j;
    if (idx < NN) rs[idx] = excl + loc[j];
  }
  if (t == 1023) rs[NN] = ps[1023];
}

__global__ void fill_csr(const int* __restrict__ src, const int* __restrict__ dst,
                         const int* __restrict__ rs, int* __restrict__ cur,
                         int* __restrict__ eidx, int* __restrict__ gsrc) {
  int e = blockIdx.x * 256 + threadIdx.x;
  if (e < EE) {
    int d = dst[e];
    int p = atomicAdd(&cur[d], 1);
    int o = rs[d] + p;
    eidx[o] = e;
    gsrc[o] = src[e];
  }
}

// ---------------- all weight transposes in one kernel -----------------------
__global__ void transpose_all(const float* __restrict__ encW0, const float* __restrict__ encW,
                              const float* __restrict__ clsW0, const float* __restrict__ clsW,
                              const float* __restrict__ eaW1, ushort* __restrict__ Wt) {
  int i = blockIdx.x * 256 + threadIdx.x;
  if (i < 8192) {                       // enc_W0: 64x128 -> [n][k]
    int k = i >> 7, n = i & 127;
    Wt[WT_ENC0 + n * 64 + k] = f2bf(encW0[i]);
  } else if (i < 73728) {               // enc_W: 4 x 128x128
    int j = i - 8192;
    int l = j >> 14, r = j & 16383, k = r >> 7, n = r & 127;
    Wt[WT_ENC + l * 16384 + n * 128 + k] = f2bf(encW[j]);
  } else if (i < 81920) {               // cls_W0
    int j = i - 73728;
    int k = j >> 7, n = j & 127;
    Wt[WT_CLS0 + n * 64 + k] = f2bf(clsW0[j]);
  } else if (i < 147456) {              // cls_W
    int j = i - 81920;
    int l = j >> 14, r = j & 16383, k = r >> 7, n = r & 127;
    Wt[WT_CLS + l * 16384 + n * 128 + k] = f2bf(clsW[j]);
  } else if (i < 278528) {              // ea_W1: 256x512 -> [n][k]
    int j = i - 147456;
    int k = j >> 9, n = j & 511;
    Wt[WT_EA1 + n * 256 + k] = f2bf(eaW1[j]);
  }
}

// ---------------- fused GIN layer, K=64 (fp32 x in, bf16 out) ---------------
// v6 = v3b (16 nodes/block, 16 lanes/node, depth-4 row pipeline, index loads
// 8 ahead) with eclamp speculation. The 517us-config kernel.
template <bool HASATT>
__global__ __launch_bounds__(256) void fused_layer64(
    const float* __restrict__ X, ushort* __restrict__ C,
    const int* __restrict__ gsrc, const int* __restrict__ rs,
    const float* __restrict__ att, const ushort* __restrict__ Bt,
    const float* __restrict__ bias) {
  __shared__ __align__(16) char smem[8448];
  ushort* Asm = (ushort*)smem;                 // [16][72] bf16 (144B rows)
  const int tid = threadIdx.x;
  const int g = tid >> 4, l = tid & 15;
  const int nb = blockIdx.x * 16;
  {
    const int n = nb + g;
    const int e0 = rs[n];
    const int deg = rs[n + 1] - e0;
    const int hi = e0 + deg - 1;
    float4 s = ((const float4*)(X + (size_t)n * 64))[l];
    float a[4] = {s.x, s.y, s.z, s.w};
    const float4* Xr = (const float4*)X;

    int i0 = gsrc[eclamp(e0 + 0, hi)];
    int i1 = gsrc[eclamp(e0 + 1, hi)];
    int i2 = gsrc[eclamp(e0 + 2, hi)];
    int i3 = gsrc[eclamp(e0 + 3, hi)];
    float4 F0 = Xr[(size_t)i0 * 16 + l];
    float4 F1 = Xr[(size_t)i1 * 16 + l];
    float4 F2 = Xr[(size_t)i2 * 16 + l];
    float4 F3 = Xr[(size_t)i3 * 16 + l];
    int G0 = gsrc[eclamp(e0 + 4, hi)];
    int G1 = gsrc[eclamp(e0 + 5, hi)];
    int G2 = gsrc[eclamp(e0 + 6, hi)];
    int G3 = gsrc[eclamp(e0 + 7, hi)];
    float W0 = 1.f, W1 = 1.f, W2 = 1.f, W3 = 1.f;
    if (HASATT) {
      W0 = att[eclamp(e0 + 0, hi)];
      W1 = att[eclamp(e0 + 1, hi)];
      W2 = att[eclamp(e0 + 2, hi)];
      W3 = att[eclamp(e0 + 3, hi)];
    }

#define FL64_STEP(F, G, W, J)                                                 \
    {                                                                         \
      if ((J) < deg) {                                                        \
        const float cw_ = HASATT ? (W) : 1.f;                                 \
        a[0] = fmaf(cw_, F.x, a[0]); a[1] = fmaf(cw_, F.y, a[1]);             \
        a[2] = fmaf(cw_, F.z, a[2]); a[3] = fmaf(cw_, F.w, a[3]);             \
      }                                                                       \
      F = Xr[(size_t)G * 16 + l];                                             \
      G = gsrc[eclamp(e0 + (J) + 8, hi)];                                     \
      if (HASATT) W = att[eclamp(e0 + (J) + 4, hi)];                          \
    }

    for (int j = 0; j < deg; j += 4) {
      FL64_STEP(F0, G0, W0, j);
      FL64_STEP(F1, G1, W1, j + 1);
      FL64_STEP(F2, G2, W2, j + 2);
      FL64_STEP(F3, G3, W3, j + 3);
    }
#undef FL64_STEP
    ushort4 o;
    o.x = f2bf(a[0]); o.y = f2bf(a[1]); o.z = f2bf(a[2]); o.w = f2bf(a[3]);
    *(ushort4*)(Asm + g * 72 + l * 4) = o;
  }
  __syncthreads();
  const int wave = tid >> 6, lane = tid & 63, quad = lane >> 4, l15 = lane & 15;
  f32x4 acc[2] = {{0.f, 0.f, 0.f, 0.f}, {0.f, 0.f, 0.f, 0.f}};
#pragma unroll
  for (int k0 = 0; k0 < 64; k0 += 32) {
    bf16x8 af = *(const bf16x8*)(Asm + l15 * 72 + k0 + quad * 8);
#pragma unroll
    for (int t = 0; t < 2; ++t) {
      int bn = wave * 32 + t * 16 + l15;
      bf16x8 bf = *(const bf16x8*)(Bt + (size_t)bn * 64 + k0 + quad * 8);
      acc[t] = __builtin_amdgcn_mfma_f32_16x16x32_bf16(af, bf, acc[t], 0, 0, 0);
    }
  }
  __syncthreads();
  float (*Csm)[132] = (float(*)[132])smem;
#pragma unroll
  for (int t = 0; t < 2; ++t) {
    int lc = wave * 32 + t * 16 + l15;
    float bs = bias[lc];
#pragma unroll
    for (int r = 0; r < 4; ++r)
      Csm[quad * 4 + r][lc] = fmaxf(acc[t][r] + bs, 0.f);
  }
  __syncthreads();
  const int r = tid >> 4, cc = (tid & 15) * 8;
  f32x4 v0 = *(const f32x4*)&Csm[r][cc];
  f32x4 v1 = *(const f32x4*)&Csm[r][cc + 4];
  uint4 o;
  o.x = pack2(v0[0], v0[1]); o.y = pack2(v0[2], v0[3]);
  o.z = pack2(v1[0], v1[1]); o.w = pack2(v1[2], v1[3]);
  *(uint4*)(C + (size_t)(nb + r) * 128 + cc) = o;
}

// ---------------- fused GIN layer, K=128 (bf16 in/out) ----------------------
// v6 = v3b with eclamp speculation. Row stride: 128 bf16 = 16 uint4.
template <bool HASATT>
__global__ __launch_bounds__(256) void fused_layer128(
    const ushort* __restrict__ Xb, ushort* __restrict__ C,
    const int* __restrict__ gsrc, const int* __restrict__ rs,
    const float* __restrict__ att, const ushort* __restrict__ Bt,
    const float* __restrict__ bias) {
  __shared__ __align__(16) char smem[8448];
  ushort* Asm = (ushort*)smem;                 // [16][136] bf16 (272B rows)
  const int tid = threadIdx.x;
  const int g = tid >> 4, l = tid & 15;
  const int nb = blockIdx.x * 16;
  {
    const int n = nb + g;
    const int e0 = rs[n];
    const int deg = rs[n + 1] - e0;
    const int hi = e0 + deg - 1;
    float a[8];
    {
      uint4 s = ((const uint4*)(Xb + (size_t)n * 128))[l];
      a[0] = bflo(s.x); a[1] = bfhi(s.x); a[2] = bflo(s.y); a[3] = bfhi(s.y);
      a[4] = bflo(s.z); a[5] = bfhi(s.z); a[6] = bflo(s.w); a[7] = bfhi(s.w);
    }
    const uint4* Xr = (const uint4*)Xb;

    int i0 = gsrc[eclamp(e0 + 0, hi)];
    int i1 = gsrc[eclamp(e0 + 1, hi)];
    int i2 = gsrc[eclamp(e0 + 2, hi)];
    int i3 = gsrc[eclamp(e0 + 3, hi)];
    uint4 F0 = Xr[(size_t)i0 * 16 + l];
    uint4 F1 = Xr[(size_t)i1 * 16 + l];
    uint4 F2 = Xr[(size_t)i2 * 16 + l];
    uint4 F3 = Xr[(size_t)i3 * 16 + l];
    int G0 = gsrc[eclamp(e0 + 4, hi)];
    int G1 = gsrc[eclamp(e0 + 5, hi)];
    int G2 = gsrc[eclamp(e0 + 6, hi)];
    int G3 = gsrc[eclamp(e0 + 7, hi)];
    float W0 = 1.f, W1 = 1.f, W2 = 1.f, W3 = 1.f;
    if (HASATT) {
      W0 = att[eclamp(e0 + 0, hi)];
      W1 = att[eclamp(e0 + 1, hi)];
      W2 = att[eclamp(e0 + 2, hi)];
      W3 = att[eclamp(e0 + 3, hi)];
    }

#define FL128_STEP(F, G, W, J)                                                \
    {                                                                         \
      if ((J) < deg) {                                                        \
        const float cw_ = HASATT ? (W) : 1.f;                                 \
        a[0] = fmaf(cw_, bflo(F.x), a[0]); a[1] = fmaf(cw_, bfhi(F.x), a[1]); \
        a[2] = fmaf(cw_, bflo(F.y), a[2]); a[3] = fmaf(cw_, bfhi(F.y), a[3]); \
        a[4] = fmaf(cw_, bflo(F.z), a[4]); a[5] = fmaf(cw_, bfhi(F.z), a[5]); \
        a[6] = fmaf(cw_, bflo(F.w), a[6]); a[7] = fmaf(cw_, bfhi(F.w), a[7]); \
      }                                                                       \
      F = Xr[(size_t)G * 16 + l];                                             \
      G = gsrc[eclamp(e0 + (J) + 8, hi)];                                     \
      if (HASATT) W = att[eclamp(e0 + (J) + 4, hi)];                          \
    }

    for (int j = 0; j < deg; j += 4) {
      FL128_STEP(F0, G0, W0, j);
      FL128_STEP(F1, G1, W1, j + 1);
      FL128_STEP(F2, G2, W2, j + 2);
      FL128_STEP(F3, G3, W3, j + 3);
    }
#undef FL128_STEP
    uint4 o;
    o.x = pack2(a[0], a[1]); o.y = pack2(a[2], a[3]);
    o.z = pack2(a[4], a[5]); o.w = pack2(a[6], a[7]);
    *(uint4*)(Asm + g * 136 + l * 8) = o;
  }
  __syncthreads();
  const int wave = tid >> 6, lane = tid & 63, quad = lane >> 4, l15 = lane & 15;
  f32x4 acc[2] = {{0.f, 0.f, 0.f, 0.f}, {0.f, 0.f, 0.f, 0.f}};
#pragma unroll
  for (int k0 = 0; k0 < 128; k0 += 32) {
    bf16x8 af = *(const bf16x8*)(Asm + l15 * 136 + k0 + quad * 8);
#pragma unroll
    for (int t = 0; t < 2; ++t) {
      int bn = wave * 32 + t * 16 + l15;
      bf16x8 bf = *(const bf16x8*)(Bt + (size_t)bn * 128 + k0 + quad * 8);
      acc[t] = __builtin_amdgcn_mfma_f32_16x16x32_bf16(af, bf, acc[t], 0, 0, 0);
    }
  }
  __syncthreads();
  float (*Csm)[132] = (float(*)[132])smem;
#pragma unroll
  for (int t = 0; t < 2; ++t) {
    int lc = wave * 32 + t * 16 + l15;
    float bs = bias[lc];
#pragma unroll
    for (int r = 0; r < 4; ++r)
      Csm[quad * 4 + r][lc] = fmaxf(acc[t][r] + bs, 0.f);
  }
  __syncthreads();
  const int r = tid >> 4, cc = (tid & 15) * 8;
  f32x4 v0 = *(const f32x4*)&Csm[r][cc];
  f32x4 v1 = *(const f32x4*)&Csm[r][cc + 4];
  uint4 o;
  o.x = pack2(v0[0], v0[1]); o.y = pack2(v0[2], v0[3]);
  o.z = pack2(v1[0], v1[1]); o.w = pack2(v1[2], v1[3]);
  *(uint4*)(C + (size_t)(nb + r) * 128 + cc) = o;
}

// ---------------- Pa+Pb fused: grid (4, 625) --------------------------------
// One block computes its 32x128 tile for BOTH Pa and Pb (bf16). A-frag loaded
// once feeds 2 MFMAs; W1t 512B rows fully used. [round 8: 55.5 -> 51.5 us]
__global__ __launch_bounds__(256) void gemm_papb(
    const ushort* __restrict__ Hb, const ushort* __restrict__ W1t,
    const float* __restrict__ b1, ushort* __restrict__ Pa, ushort* __restrict__ Pb) {
  __shared__ float lds[32][132];
  const int tid = threadIdx.x;
  const int wave = tid >> 6, lane = tid & 63, quad = lane >> 4, l15 = lane & 15;
  const int mh = wave >> 1, nh = wave & 1;
  const int col0 = blockIdx.x * 128;
  const int row0 = blockIdx.y * 32;
  f32x4 accA[4] = {{0.f, 0.f, 0.f, 0.f}, {0.f, 0.f, 0.f, 0.f},
                   {0.f, 0.f, 0.f, 0.f}, {0.f, 0.f, 0.f, 0.f}};
  f32x4 accB[4] = {{0.f, 0.f, 0.f, 0.f}, {0.f, 0.f, 0.f, 0.f},
                   {0.f, 0.f, 0.f, 0.f}, {0.f, 0.f, 0.f, 0.f}};
  const ushort* Ap = Hb + (size_t)(row0 + mh * 16 + l15) * 128 + quad * 8;
#pragma unroll
  for (int k0 = 0; k0 < 128; k0 += 32) {
    bf16x8 af = *(const bf16x8*)(Ap + k0);
#pragma unroll
    for (int t = 0; t < 4; ++t) {
      int bn = col0 + nh * 64 + t * 16 + l15;
      const ushort* Brow = W1t + (size_t)bn * 256 + k0 + quad * 8;
      bf16x8 bfa = *(const bf16x8*)(Brow);
      bf16x8 bfb = *(const bf16x8*)(Brow + 128);
      accA[t] = __builtin_amdgcn_mfma_f32_16x16x32_bf16(af, bfa, accA[t], 0, 0, 0);
      accB[t] = __builtin_amdgcn_mfma_f32_16x16x32_bf16(af, bfb, accB[t], 0, 0, 0);
    }
  }
#pragma unroll
  for (int pass = 0; pass < 2; ++pass) {
    if (pass) __syncthreads();          // previous pass's readers done
#pragma unroll
    for (int t = 0; t < 4; ++t) {
      int lc = nh * 64 + t * 16 + l15;
      float bs = pass ? 0.f : b1[col0 + lc];
      f32x4 av = pass ? accB[t] : accA[t];
#pragma unroll
      for (int r = 0; r < 4; ++r)
        lds[mh * 16 + quad * 4 + r][lc] = av[r] + bs;
    }
    __syncthreads();
    ushort* C = pass ? Pb : Pa;
    const int r = tid >> 3, c0 = (tid & 7) * 16;
    ushort* Cp = C + (size_t)(row0 + r) * 512 + col0 + c0;
#pragma unroll
    for (int k = 0; k < 4; ++k) {
      f32x4 v = *(const f32x4*)&lds[r][c0 + k * 4];
      ushort4 o;
      o.x = f2bf(v[0]); o.y = f2bf(v[1]); o.z = f2bf(v[2]); o.w = f2bf(v[3]);
      *(ushort4*)(Cp + k * 4) = o;
    }
  }
}

// ---------------- edge MLP layer 2: one full wave per dst node --------------
// v6 = pipelined wave-per-node (coalesced full-row reads, butterfly) with
// eclamp speculation. [round 8: 51.5 us, FETCH at the 8-XCD compulsory floor]
__global__ __launch_bounds__(256) void edge_pe_csr(
    const ushort* __restrict__ Pa, const ushort* __restrict__ Pb,
    const int* __restrict__ gsrc, const int* __restrict__ rs,
    const float* __restrict__ W2, const float* __restrict__ b2,
    float* __restrict__ pe) {
  const int lane = threadIdx.x & 63;
  const int n = blockIdx.x * 4 + (threadIdx.x >> 6);
  const int e0 = rs[n];
  const int deg = rs[n + 1] - e0;
  if (deg <= 0) return;
  const int hi = e0 + deg - 1;
  float w[8], pb[8];
  {
    const float4* w2v = (const float4*)(W2 + lane * 8);
    float4 t0 = w2v[0], t1 = w2v[1];
    w[0] = t0.x; w[1] = t0.y; w[2] = t0.z; w[3] = t0.w;
    w[4] = t1.x; w[5] = t1.y; w[6] = t1.z; w[7] = t1.w;
    uint4 b = ((const uint4*)(Pb + (size_t)n * 512))[lane];
    pb[0] = bflo(b.x); pb[1] = bfhi(b.x); pb[2] = bflo(b.y); pb[3] = bfhi(b.y);
    pb[4] = bflo(b.z); pb[5] = bfhi(b.z); pb[6] = bflo(b.w); pb[7] = bfhi(b.w);
  }
  const float b2v = b2[0];
  const uint4* Par = (const uint4*)Pa;

  int i0 = gsrc[eclamp(e0 + 0, hi)];
  int i1 = gsrc[eclamp(e0 + 1, hi)];
  int i2 = gsrc[eclamp(e0 + 2, hi)];
  int i3 = gsrc[eclamp(e0 + 3, hi)];
  uint4 F0 = Par[(size_t)i0 * 64 + lane];
  uint4 F1 = Par[(size_t)i1 * 64 + lane];
  uint4 F2 = Par[(size_t)i2 * 64 + lane];
  uint4 F3 = Par[(size_t)i3 * 64 + lane];
  int G0 = gsrc[eclamp(e0 + 4, hi)];
  int G1 = gsrc[eclamp(e0 + 5, hi)];
  int G2 = gsrc[eclamp(e0 + 6, hi)];
  int G3 = gsrc[eclamp(e0 + 7, hi)];

#define PE_STEP(F, G, J)                                                      \
  {                                                                           \
    if ((J) < deg) {                                                          \
      float pa[8] = {bflo(F.x), bfhi(F.x), bflo(F.y), bfhi(F.y),              \
                     bflo(F.z), bfhi(F.z), bflo(F.w), bfhi(F.w)};             \
      float acc = 0.f;                                                        \
      _Pragma("unroll")                                                       \
      for (int jj = 0; jj < 8; ++jj) acc += fmaxf(pa[jj] + pb[jj], 0.f) * w[jj]; \
      _Pragma("unroll")                                                       \
      for (int off = 32; off; off >>= 1) acc += __shfl_xor(acc, off);         \
      if (lane == 0) pe[e0 + (J)] = acc + b2v;                                \
    }                                                                         \
    F = Par[(size_t)G * 64 + lane];                                           \
    G = gsrc[eclamp(e0 + (J) + 8, hi)];                                       \
  }

  for (int j = 0; j < deg; j += 4) {
    PE_STEP(F0, G0, j);
    PE_STEP(F1, G1, j + 1);
    PE_STEP(F2, G2, j + 2);
    PE_STEP(F3, G3, j + 3);
  }
#undef PE_STEP
}

// ---------------- pe statistics (sum, sumsq, min, max) ----------------------
__global__ __launch_bounds__(256) void pe_stats(const float* __restrict__ pe,
                                                float* __restrict__ scal) {
  __shared__ float r1[256], r2[256], r3[256], r4[256];
  int tid = threadIdx.x;
  float s = 0.f, q = 0.f, mn = 3.0e38f, mx = -3.0e38f;
  for (int i = blockIdx.x * 256 + tid; i < EE; i += gridDim.x * 256) {
    float v = pe[i];
    s += v; q = fmaf(v, v, q);
    mn = fminf(mn, v); mx = fmaxf(mx, v);
  }
  r1[tid] = s; r2[tid] = q; r3[tid] = mn; r4[tid] = mx;
  __syncthreads();
  for (int k = 128; k > 0; k >>= 1) {
    if (tid < k) {
      r1[tid] += r1[tid + k];
      r2[tid] += r2[tid + k];
      r3[tid] = fminf(r3[tid], r3[tid + k]);
      r4[tid] = fmaxf(r4[tid], r4[tid + k]);
    }
    __syncthreads();
  }
  if (tid == 0) {
    unsafeAtomicAdd(&scal[0], r1[0]);
    unsafeAtomicAdd(&scal[1], r2[0]);
    atomicMin((unsigned*)scal + 2, ordf(r3[0]));
    atomicMax((unsigned*)scal + 3, ordf(r4[0]));
  }
}

// ---------------- delta + histogram (CSR order; u gathered via eidx) --------
__global__ __launch_bounds__(256) void edge_delta_hist(
    const float* __restrict__ pe, const float* __restrict__ u,
    const int* __restrict__ eidx, float* __restrict__ delta,
    float* __restrict__ hist, const float* __restrict__ scal) {
  __shared__ float cnt_s[NBINS], sum_s[NBINS];
  for (int b = threadIdx.x; b < NBINS; b += 256) { cnt_s[b] = 0.f; sum_s[b] = 0.f; }
  float sum = scal[0], ssq = scal[1];
  float mn = unordf(((const unsigned*)scal)[2]);
  float mx = unordf(((const unsigned*)scal)[3]);
  float mu = sum / (float)EE;
  float var = (ssq - sum * sum / (float)EE) / (float)(EE - 1);
  float istd = rsqrtf(fmaxf(var, 1e-30f));
  float shift = (mn - mu) * istd + (mx - mu) * istd;
  __syncthreads();
  for (int i = blockIdx.x * 256 + threadIdx.x; i < EE; i += gridDim.x * 256) {
    float uu = u[eidx[i]];
    float atts = (pe[i] - mu) * istd;
    float g = -logf(-logf(uu + EPSF) + EPSF);
    float dl = 2.0f * (atts + g) - shift;
    delta[i] = dl;
    float dcl = fminf(fmaxf(dl, -HRANGE), HRANGE * 0.9999f);
    int b = (int)((dcl + HRANGE) * ((float)NBINS / (2.0f * HRANGE)));
    b = min(max(b, 0), NBINS - 1);
    atomicAdd(&cnt_s[b], 1.0f);
    atomicAdd(&sum_s[b], dcl);
  }
  __syncthreads();
  for (int b = threadIdx.x; b < NBINS; b += 256) {
    float c = cnt_s[b];
    if (c != 0.f) {
      unsafeAtomicAdd(&hist[b], c);
      unsafeAtomicAdd(&hist[NBINS + b], sum_s[b]);
    }
  }
}

// ---------------- scalar Sinkhorn recursion (single wave) -------------------
__global__ __launch_bounds__(64) void sinkhorn_iter(const float* __restrict__ hist,
                                                    float* __restrict__ scal) {
  const int lane = threadIdx.x;
  float cnt[32], mean[32];
#pragma unroll
  for (int b = 0; b < 32; ++b) {
    int idx = b * 64 + lane;
    float c = hist[idx];
    cnt[b] = c;
    mean[b] = (c > 0.f) ? hist[NBINS + idx] / c : 0.f;
  }
  const float LRD = -1.0986122886681098f;
  float S = 0.f, Zfin = 0.f;
  for (int it = 0; it < 30; ++it) {
    float p = 0.f;
#pragma unroll
    for (int b = 0; b < 32; ++b)
      if (cnt[b] > 0.f) p += cnt[b] / (1.f + expf(-(mean[b] + S)));
#pragma unroll
    for (int off = 32; off; off >>= 1) p += __shfl_xor(p, off);
    if (it < 29)
      S += logf(fmaxf((float)EE - p, 1.0f)) - logf(p) + LRD;
    else
      Zfin = p;
  }
  if (lane == 0) {
    scal[8] = S;
    scal[9] = ((float)EE * 0.25f) / Zfin;
  }
}

// ---------------- T_i (CSR order) -------------------------------------------
__global__ void compute_T(const float* __restrict__ delta,
                          const float* __restrict__ scal,
                          float* __restrict__ Ta) {
  int i = blockIdx.x * 256 + threadIdx.x;
  if (i >= EE) return;
  float S = scal[8], sc = scal[9];
  Ta[i] = sc / (1.f + expf(-(delta[i] + S)));
}

// ---------------- mean pooling (4 independent partials) + head --------------
__global__ __launch_bounds__(128) void col_mean(const ushort* __restrict__ Hc,
                                                float* __restrict__ rep) {
  int c = threadIdx.x;
  const int g = gridDim.x;
  float p0 = 0.f, p1 = 0.f, p2 = 0.f, p3 = 0.f;
  int n = blockIdx.x;
  for (; n + 3 * g < NN; n += 4 * g) {
    p0 += bf2f(Hc[(size_t)n * 128 + c]);
    p1 += bf2f(Hc[(size_t)(n + g) * 128 + c]);
    p2 += bf2f(Hc[(size_t)(n + 2 * g) * 128 + c]);
    p3 += bf2f(Hc[(size_t)(n + 3 * g) * 128 + c]);
  }
  for (; n < NN; n += g) p0 += bf2f(Hc[(size_t)n * 128 + c]);
  unsafeAtomicAdd(&rep[c], (p0 + p1) + (p2 + p3));
}

__global__ __launch_bounds__(128) void head_kernel(const float* __restrict__ repsum,
                                                   const float* __restrict__ hW,
                                                   const float* __restrict__ hb,
                                                   float* __restrict__ out) {
  __shared__ float rep[128];
  int tid = threadIdx.x;
  if (tid < 128) rep[tid] = repsum[tid] * (1.0f / (float)NN);
  __syncthreads();
  if (tid < 10) {
    float a = hb[tid];
#pragma unroll
    for (int c = 0; c < 128; c++) a = fmaf(rep[c], hW[c * 10 + tid], a);
    out[tid] = a;
  }
}

// ---------------- launch ----------------------------------------------------
extern "C" void kernel_launch(void* const* d_in, const int* in_sizes, int n_in,
                              void* d_out, int out_size, void* d_ws, size_t ws_size,
                              hipStream_t stream) {
  const float* x      = (const float*)d_in[0];
  const int*   ei     = (const int*)d_in[1];
  const float* u      = (const float*)d_in[2];
  const float* enc_W0 = (const float*)d_in[3];
  const float* enc_b0 = (const float*)d_in[4];
  const float* enc_W  = (const float*)d_in[5];
  const float* enc_b  = (const float*)d_in[6];
  const float* ea_W1  = (const float*)d_in[7];
  const float* ea_b1  = (const float*)d_in[8];
  const float* ea_W2  = (const float*)d_in[9];
  const float* ea_b2  = (const float*)d_in[10];
  const float* cls_W0 = (const float*)d_in[11];
  const float* cls_b0 = (const float*)d_in[12];
  const float* cls_W  = (const float*)d_in[13];
  const float* cls_b  = (const float*)d_in[14];
  const float* head_W = (const float*)d_in[15];
  const float* head_b = (const float*)d_in[16];
  const int* src  = ei;
  const int* dstp = ei + EE;

  float* wsF = (float*)d_ws;
  int*   wsI = (int*)d_ws;
  int* deg  = wsI + OFF_DEG;
  int* rs   = wsI + OFF_RS;
  int* cur  = wsI + OFF_CUR;
  int* eix  = wsI + OFF_EIX;
  int* gsrc = wsI + OFF_GSRC;
  ushort* B0 = (ushort*)(wsF + OFF_B0);
  ushort* B1 = (ushort*)(wsF + OFF_B1);
  ushort* Pa = (ushort*)(wsF + OFF_PA);
  ushort* Pb = (ushort*)(wsF + OFF_PB);
  float* pe   = wsF + OFF_PE;
  float* dl   = wsF + OFF_DL;
  float* Ta   = wsF + OFF_TT;
  float* hist = wsF + OFF_HIST;
  float* scal = wsF + OFF_SCAL;
  float* rep  = wsF + OFF_REP;
  ushort* Wt  = (ushort*)(wsF + OFF_WT);
  float* out = (float*)d_out;

  init_ws<<<(NN + 255) / 256, 256, 0, stream>>>(deg, cur, hist, scal, rep);
  count_deg<<<(EE + 255) / 256, 256, 0, stream>>>(dstp, deg);
  scan_deg<<<1, 1024, 0, stream>>>(deg, rs);
  fill_csr<<<(EE + 255) / 256, 256, 0, stream>>>(src, dstp, rs, cur, eix, gsrc);
  transpose_all<<<1088, 256, 0, stream>>>(enc_W0, enc_W, cls_W0, cls_W, ea_W1, Wt);

  const int GB = NN / 16;  // 1250 (16 nodes per block) — the 517us config

  // encoder GIN stack (att = 1)
  fused_layer64<false><<<GB, 256, 0, stream>>>(x, B0, gsrc, rs, nullptr, Wt + WT_ENC0, enc_b0);
  {
    ushort* in = B0; ushort* outb = B1;
    for (int l = 0; l < 4; l++) {
      fused_layer128<false><<<GB, 256, 0, stream>>>(in, outb, gsrc, rs, nullptr,
                                                    Wt + WT_ENC + (size_t)l * 16384,
                                                    enc_b + (size_t)l * 128);
      ushort* t = in; in = outb; outb = t;
    }
  }
  // encoder output in B0

  gemm_papb<<<dim3(4, NN / 32), 256, 0, stream>>>(B0, Wt + WT_EA1, ea_b1, Pa, Pb);
  edge_pe_csr<<<NN / 4, 256, 0, stream>>>(Pa, Pb, gsrc, rs, ea_W2, ea_b2, pe);

  pe_stats<<<512, 256, 0, stream>>>(pe, scal);
  edge_delta_hist<<<128, 256, 0, stream>>>(pe, u, eix, dl, hist, scal);
  sinkhorn_iter<<<1, 64, 0, stream>>>(hist, scal);
  compute_T<<<(EE + 255) / 256, 256, 0, stream>>>(dl, scal, Ta);

  // classifier GIN stack (att = T, CSR-ordered)
  fused_layer64<true><<<GB, 256, 0, stream>>>(x, B0, gsrc, rs, Ta, Wt + WT_CLS0, cls_b0);
  {
    ushort* in = B0; ushort* outb = B1;
    for (int l = 0; l < 4; l++) {
      fused_layer128<true><<<GB, 256, 0, stream>>>(in, outb, gsrc, rs, Ta,
                                                   Wt + WT_CLS + (size_t)l * 16384,
                                                   cls_b + (size_t)l * 128);
      ushort* t = in; in = outb; outb = t;
    }
  }

  col_mean<<<256, 128, 0, stream>>>(B0, rep);
  head_kernel<<<1, 128, 0, stream>>>(rep, head_W, head_b, out);
}

// Round 13
// 499.075 us; speedup vs baseline: 1.1903x; 1.0434x over previous
//
#include <hip/hip_runtime.h>
#include <math.h>

#define NN 20000
#define EE 320000
#define NBINS 2048
#define HRANGE 64.0f
#define EPSF 1e-20f

typedef __attribute__((ext_vector_type(8))) short bf16x8;
typedef __attribute__((ext_vector_type(4))) float f32x4;

// ---------------- workspace layout (f32-slot offsets, all 16B-aligned) -----
constexpr size_t OFF_DEG  = 0;                    // NN ints
constexpr size_t OFF_RS   = 20000;                // NN+1 ints (+pad)
constexpr size_t OFF_CUR  = 40008;                // NN ints
constexpr size_t OFF_EIX  = 60008;                // EE ints
constexpr size_t OFF_GSRC = 380008;               // EE ints
constexpr size_t OFF_B0   = 700008;               // NN*128 bf16 (1280000 slots)
constexpr size_t OFF_B1   = 1980008;              // NN*128 bf16
constexpr size_t OFF_PA   = 3260008;              // NN*512 bf16
constexpr size_t OFF_PB   = 8380008;              // NN*512 bf16
constexpr size_t OFF_PE   = 13500008;             // EE f32 (CSR order)
constexpr size_t OFF_DL   = 13820008;             // EE f32 (CSR order)
constexpr size_t OFF_TT   = 14140008;             // EE f32 (CSR order)
constexpr size_t OFF_HIST = 14460008;             // 2*NBINS f32
constexpr size_t OFF_SCAL = 14464104;             // 32 f32
constexpr size_t OFF_REP  = 14464136;             // 128 f32
constexpr size_t OFF_WT   = 14464264;             // 278528 bf16
// WT sub-offsets (bf16 units):
constexpr size_t WT_ENC0 = 0;         // 128x64 (n-major)
constexpr size_t WT_ENC  = 8192;      // 4 x 128x128
constexpr size_t WT_CLS0 = 73728;     // 128x64
constexpr size_t WT_CLS  = 81920;     // 4 x 128x128
constexpr size_t WT_EA1  = 147456;    // 512x256

__device__ __forceinline__ unsigned ordf(float f) {
  unsigned b = __float_as_uint(f);
  return (b >> 31) ? ~b : (b | 0x80000000u);
}
__device__ __forceinline__ float unordf(unsigned u) {
  unsigned b = (u >> 31) ? (u ^ 0x80000000u) : ~u;
  return __uint_as_float(b);
}
__device__ __forceinline__ ushort f2bf(float f) {   // RNE
  unsigned u = __float_as_uint(f);
  u += 0x7FFFu + ((u >> 16) & 1u);
  return (ushort)(u >> 16);
}
__device__ __forceinline__ unsigned pack2(float x, float y) {
  return (unsigned)f2bf(x) | ((unsigned)f2bf(y) << 16);
}
__device__ __forceinline__ float bf2f(ushort h) {
  return __uint_as_float(((unsigned)h) << 16);
}
__device__ __forceinline__ float bflo(unsigned v) { return __uint_as_float(v << 16); }
__device__ __forceinline__ float bfhi(unsigned v) { return __uint_as_float(v & 0xFFFF0000u); }
// speculative-slot clamp: keep prefetch addresses inside the node's own edge
// range so overshoot re-reads the LAST row (L1/L2 hit) instead of fetching a
// random far row. Clamped slots are never accumulated (guarded) -> bit-exact.
// [round 7: -12.6us total, edge_pe FETCH waste removed]
// NOTE (round 10): fp8-e4m3 Pa storage FAILED correctness (absmax 92) —
// Pa magnitudes exceed fp8's ±448 range. Unscaled low-precision not viable.
__device__ __forceinline__ int eclamp(int j, int hi) {
  return max(min(j, hi), 0);
}

// ---------------- init ------------------------------------------------------
__global__ void init_ws(int* deg, int* cur, float* hist, float* scal, float* rep) {
  int i = blockIdx.x * blockDim.x + threadIdx.x;
  if (i < NN) { deg[i] = 0; cur[i] = 0; }
  if (i < 2 * NBINS) hist[i] = 0.f;
  if (i < 128) rep[i] = 0.f;
  if (i < 32) {
    if (i == 2)      ((unsigned*)scal)[2] = 0xFFFFFFFFu;
    else if (i == 3) ((unsigned*)scal)[3] = 0u;
    else scal[i] = 0.f;
  }
}

// ---------------- CSR build -------------------------------------------------
__global__ void count_deg(const int* __restrict__ dst, int* __restrict__ deg) {
  int e = blockIdx.x * 256 + threadIdx.x;
  if (e < EE) atomicAdd(&deg[dst[e]], 1);
}

__global__ __launch_bounds__(1024) void scan_deg(const int* __restrict__ deg,
                                                 int* __restrict__ rs) {
  __shared__ int ps[1024];
  const int t = threadIdx.x;
  const int base = t * 20;
  int loc[20];
  int s = 0;
#pragma unroll
  for (int j = 0; j < 20; ++j) {
    int idx = base + j;
    int v = (idx < NN) ? deg[idx] : 0;
    loc[j] = s;
    s += v;
  }
  ps[t] = s;
  __syncthreads();
  for (int off = 1; off < 1024; off <<= 1) {
    int x = (t >= off) ? ps[t - off] : 0;
    __syncthreads();
    ps[t] += x;
    __syncthreads();
  }
  const int excl = ps[t] - s;
#pragma unroll
  for (int j = 0; j < 20; ++j) {
    int idx = base + j;
    if (idx < NN) rs[idx] = excl + loc[j];
  }
  if (t == 1023) rs[NN] = ps[1023];
}

__global__ void fill_csr(const int* __restrict__ src, const int* __restrict__ dst,
                         const int* __restrict__ rs, int* __restrict__ cur,
                         int* __restrict__ eidx, int* __restrict__ gsrc) {
  int e = blockIdx.x * 256 + threadIdx.x;
  if (e < EE) {
    int d = dst[e];
    int p = atomicAdd(&cur[d], 1);
    int o = rs[d] + p;
    eidx[o] = e;
    gsrc[o] = src[e];
  }
}

// ---------------- all weight transposes in one kernel -----------------------
__global__ void transpose_all(const float* __restrict__ encW0, const float* __restrict__ encW,
                              const float* __restrict__ clsW0, const float* __restrict__ clsW,
                              const float* __restrict__ eaW1, ushort* __restrict__ Wt) {
  int i = blockIdx.x * 256 + threadIdx.x;
  if (i < 8192) {                       // enc_W0: 64x128 -> [n][k]
    int k = i >> 7, n = i & 127;
    Wt[WT_ENC0 + n * 64 + k] = f2bf(encW0[i]);
  } else if (i < 73728) {               // enc_W: 4 x 128x128
    int j = i - 8192;
    int l = j >> 14, r = j & 16383, k = r >> 7, n = r & 127;
    Wt[WT_ENC + l * 16384 + n * 128 + k] = f2bf(encW[j]);
  } else if (i < 81920) {               // cls_W0
    int j = i - 73728;
    int k = j >> 7, n = j & 127;
    Wt[WT_CLS0 + n * 64 + k] = f2bf(clsW0[j]);
  } else if (i < 147456) {              // cls_W
    int j = i - 81920;
    int l = j >> 14, r = j & 16383, k = r >> 7, n = r & 127;
    Wt[WT_CLS + l * 16384 + n * 128 + k] = f2bf(clsW[j]);
  } else if (i < 278528) {              // ea_W1: 256x512 -> [n][k]
    int j = i - 147456;
    int k = j >> 9, n = j & 511;
    Wt[WT_EA1 + n * 256 + k] = f2bf(eaW1[j]);
  }
}

// ---------------- fused GIN layer, K=64 (fp32 x in, bf16 out) ---------------
// v6 = v3b (16 nodes/block, 16 lanes/node, depth-4 row pipeline, index loads
// 8 ahead) with eclamp speculation. The 517-521us-config kernel.
template <bool HASATT>
__global__ __launch_bounds__(256) void fused_layer64(
    const float* __restrict__ X, ushort* __restrict__ C,
    const int* __restrict__ gsrc, const int* __restrict__ rs,
    const float* __restrict__ att, const ushort* __restrict__ Bt,
    const float* __restrict__ bias) {
  __shared__ __align__(16) char smem[8448];
  ushort* Asm = (ushort*)smem;                 // [16][72] bf16 (144B rows)
  const int tid = threadIdx.x;
  const int g = tid >> 4, l = tid & 15;
  const int nb = blockIdx.x * 16;
  {
    const int n = nb + g;
    const int e0 = rs[n];
    const int deg = rs[n + 1] - e0;
    const int hi = e0 + deg - 1;
    float4 s = ((const float4*)(X + (size_t)n * 64))[l];
    float a[4] = {s.x, s.y, s.z, s.w};
    const float4* Xr = (const float4*)X;

    int i0 = gsrc[eclamp(e0 + 0, hi)];
    int i1 = gsrc[eclamp(e0 + 1, hi)];
    int i2 = gsrc[eclamp(e0 + 2, hi)];
    int i3 = gsrc[eclamp(e0 + 3, hi)];
    float4 F0 = Xr[(size_t)i0 * 16 + l];
    float4 F1 = Xr[(size_t)i1 * 16 + l];
    float4 F2 = Xr[(size_t)i2 * 16 + l];
    float4 F3 = Xr[(size_t)i3 * 16 + l];
    int G0 = gsrc[eclamp(e0 + 4, hi)];
    int G1 = gsrc[eclamp(e0 + 5, hi)];
    int G2 = gsrc[eclamp(e0 + 6, hi)];
    int G3 = gsrc[eclamp(e0 + 7, hi)];
    float W0 = 1.f, W1 = 1.f, W2 = 1.f, W3 = 1.f;
    if (HASATT) {
      W0 = att[eclamp(e0 + 0, hi)];
      W1 = att[eclamp(e0 + 1, hi)];
      W2 = att[eclamp(e0 + 2, hi)];
      W3 = att[eclamp(e0 + 3, hi)];
    }

#define FL64_STEP(F, G, W, J)                                                 \
    {                                                                         \
      if ((J) < deg) {                                                        \
        const float cw_ = HASATT ? (W) : 1.f;                                 \
        a[0] = fmaf(cw_, F.x, a[0]); a[1] = fmaf(cw_, F.y, a[1]);             \
        a[2] = fmaf(cw_, F.z, a[2]); a[3] = fmaf(cw_, F.w, a[3]);             \
      }                                                                       \
      F = Xr[(size_t)G * 16 + l];                                             \
      G = gsrc[eclamp(e0 + (J) + 8, hi)];                                     \
      if (HASATT) W = att[eclamp(e0 + (J) + 4, hi)];                          \
    }

    for (int j = 0; j < deg; j += 4) {
      FL64_STEP(F0, G0, W0, j);
      FL64_STEP(F1, G1, W1, j + 1);
      FL64_STEP(F2, G2, W2, j + 2);
      FL64_STEP(F3, G3, W3, j + 3);
    }
#undef FL64_STEP
    ushort4 o;
    o.x = f2bf(a[0]); o.y = f2bf(a[1]); o.z = f2bf(a[2]); o.w = f2bf(a[3]);
    *(ushort4*)(Asm + g * 72 + l * 4) = o;
  }
  __syncthreads();
  const int wave = tid >> 6, lane = tid & 63, quad = lane >> 4, l15 = lane & 15;
  f32x4 acc[2] = {{0.f, 0.f, 0.f, 0.f}, {0.f, 0.f, 0.f, 0.f}};
#pragma unroll
  for (int k0 = 0; k0 < 64; k0 += 32) {
    bf16x8 af = *(const bf16x8*)(Asm + l15 * 72 + k0 + quad * 8);
#pragma unroll
    for (int t = 0; t < 2; ++t) {
      int bn = wave * 32 + t * 16 + l15;
      bf16x8 bf = *(const bf16x8*)(Bt + (size_t)bn * 64 + k0 + quad * 8);
      acc[t] = __builtin_amdgcn_mfma_f32_16x16x32_bf16(af, bf, acc[t], 0, 0, 0);
    }
  }
  __syncthreads();
  float (*Csm)[132] = (float(*)[132])smem;
#pragma unroll
  for (int t = 0; t < 2; ++t) {
    int lc = wave * 32 + t * 16 + l15;
    float bs = bias[lc];
#pragma unroll
    for (int r = 0; r < 4; ++r)
      Csm[quad * 4 + r][lc] = fmaxf(acc[t][r] + bs, 0.f);
  }
  __syncthreads();
  const int r = tid >> 4, cc = (tid & 15) * 8;
  f32x4 v0 = *(const f32x4*)&Csm[r][cc];
  f32x4 v1 = *(const f32x4*)&Csm[r][cc + 4];
  uint4 o;
  o.x = pack2(v0[0], v0[1]); o.y = pack2(v0[2], v0[3]);
  o.z = pack2(v1[0], v1[1]); o.w = pack2(v1[2], v1[3]);
  *(uint4*)(C + (size_t)(nb + r) * 128 + cc) = o;
}

// ---------------- fused GIN layer, K=128 (bf16 in/out) ----------------------
// v6 = v3b with eclamp speculation. Row stride: 128 bf16 = 16 uint4.
template <bool HASATT>
__global__ __launch_bounds__(256) void fused_layer128(
    const ushort* __restrict__ Xb, ushort* __restrict__ C,
    const int* __restrict__ gsrc, const int* __restrict__ rs,
    const float* __restrict__ att, const ushort* __restrict__ Bt,
    const float* __restrict__ bias) {
  __shared__ __align__(16) char smem[8448];
  ushort* Asm = (ushort*)smem;                 // [16][136] bf16 (272B rows)
  const int tid = threadIdx.x;
  const int g = tid >> 4, l = tid & 15;
  const int nb = blockIdx.x * 16;
  {
    const int n = nb + g;
    const int e0 = rs[n];
    const int deg = rs[n + 1] - e0;
    const int hi = e0 + deg - 1;
    float a[8];
    {
      uint4 s = ((const uint4*)(Xb + (size_t)n * 128))[l];
      a[0] = bflo(s.x); a[1] = bfhi(s.x); a[2] = bflo(s.y); a[3] = bfhi(s.y);
      a[4] = bflo(s.z); a[5] = bfhi(s.z); a[6] = bflo(s.w); a[7] = bfhi(s.w);
    }
    const uint4* Xr = (const uint4*)Xb;

    int i0 = gsrc[eclamp(e0 + 0, hi)];
    int i1 = gsrc[eclamp(e0 + 1, hi)];
    int i2 = gsrc[eclamp(e0 + 2, hi)];
    int i3 = gsrc[eclamp(e0 + 3, hi)];
    uint4 F0 = Xr[(size_t)i0 * 16 + l];
    uint4 F1 = Xr[(size_t)i1 * 16 + l];
    uint4 F2 = Xr[(size_t)i2 * 16 + l];
    uint4 F3 = Xr[(size_t)i3 * 16 + l];
    int G0 = gsrc[eclamp(e0 + 4, hi)];
    int G1 = gsrc[eclamp(e0 + 5, hi)];
    int G2 = gsrc[eclamp(e0 + 6, hi)];
    int G3 = gsrc[eclamp(e0 + 7, hi)];
    float W0 = 1.f, W1 = 1.f, W2 = 1.f, W3 = 1.f;
    if (HASATT) {
      W0 = att[eclamp(e0 + 0, hi)];
      W1 = att[eclamp(e0 + 1, hi)];
      W2 = att[eclamp(e0 + 2, hi)];
      W3 = att[eclamp(e0 + 3, hi)];
    }

#define FL128_STEP(F, G, W, J)                                                \
    {                                                                         \
      if ((J) < deg) {                                                        \
        const float cw_ = HASATT ? (W) : 1.f;                                 \
        a[0] = fmaf(cw_, bflo(F.x), a[0]); a[1] = fmaf(cw_, bfhi(F.x), a[1]); \
        a[2] = fmaf(cw_, bflo(F.y), a[2]); a[3] = fmaf(cw_, bfhi(F.y), a[3]); \
        a[4] = fmaf(cw_, bflo(F.z), a[4]); a[5] = fmaf(cw_, bfhi(F.z), a[5]); \
        a[6] = fmaf(cw_, bflo(F.w), a[6]); a[7] = fmaf(cw_, bfhi(F.w), a[7]); \
      }                                                                       \
      F = Xr[(size_t)G * 16 + l];                                             \
      G = gsrc[eclamp(e0 + (J) + 8, hi)];                                     \
      if (HASATT) W = att[eclamp(e0 + (J) + 4, hi)];                          \
    }

    for (int j = 0; j < deg; j += 4) {
      FL128_STEP(F0, G0, W0, j);
      FL128_STEP(F1, G1, W1, j + 1);
      FL128_STEP(F2, G2, W2, j + 2);
      FL128_STEP(F3, G3, W3, j + 3);
    }
#undef FL128_STEP
    uint4 o;
    o.x = pack2(a[0], a[1]); o.y = pack2(a[2], a[3]);
    o.z = pack2(a[4], a[5]); o.w = pack2(a[6], a[7]);
    *(uint4*)(Asm + g * 136 + l * 8) = o;
  }
  __syncthreads();
  const int wave = tid >> 6, lane = tid & 63, quad = lane >> 4, l15 = lane & 15;
  f32x4 acc[2] = {{0.f, 0.f, 0.f, 0.f}, {0.f, 0.f, 0.f, 0.f}};
#pragma unroll
  for (int k0 = 0; k0 < 128; k0 += 32) {
    bf16x8 af = *(const bf16x8*)(Asm + l15 * 136 + k0 + quad * 8);
#pragma unroll
    for (int t = 0; t < 2; ++t) {
      int bn = wave * 32 + t * 16 + l15;
      bf16x8 bf = *(const bf16x8*)(Bt + (size_t)bn * 128 + k0 + quad * 8);
      acc[t] = __builtin_amdgcn_mfma_f32_16x16x32_bf16(af, bf, acc[t], 0, 0, 0);
    }
  }
  __syncthreads();
  float (*Csm)[132] = (float(*)[132])smem;
#pragma unroll
  for (int t = 0; t < 2; ++t) {
    int lc = wave * 32 + t * 16 + l15;
    float bs = bias[lc];
#pragma unroll
    for (int r = 0; r < 4; ++r)
      Csm[quad * 4 + r][lc] = fmaxf(acc[t][r] + bs, 0.f);
  }
  __syncthreads();
  const int r = tid >> 4, cc = (tid & 15) * 8;
  f32x4 v0 = *(const f32x4*)&Csm[r][cc];
  f32x4 v1 = *(const f32x4*)&Csm[r][cc + 4];
  uint4 o;
  o.x = pack2(v0[0], v0[1]); o.y = pack2(v0[2], v0[3]);
  o.z = pack2(v1[0], v1[1]); o.w = pack2(v1[2], v1[3]);
  *(uint4*)(C + (size_t)(nb + r) * 128 + cc) = o;
}

// ---------------- Pa+Pb fused: grid (4, 625) --------------------------------
// One block computes its 32x128 tile for BOTH Pa and Pb (bf16). A-frag loaded
// once feeds 2 MFMAs; W1t 512B rows fully used. [round 8: 55.5 -> 51.5 us]
__global__ __launch_bounds__(256) void gemm_papb(
    const ushort* __restrict__ Hb, const ushort* __restrict__ W1t,
    const float* __restrict__ b1, ushort* __restrict__ Pa, ushort* __restrict__ Pb) {
  __shared__ float lds[32][132];
  const int tid = threadIdx.x;
  const int wave = tid >> 6, lane = tid & 63, quad = lane >> 4, l15 = lane & 15;
  const int mh = wave >> 1, nh = wave & 1;
  const int col0 = blockIdx.x * 128;
  const int row0 = blockIdx.y * 32;
  f32x4 accA[4] = {{0.f, 0.f, 0.f, 0.f}, {0.f, 0.f, 0.f, 0.f},
                   {0.f, 0.f, 0.f, 0.f}, {0.f, 0.f, 0.f, 0.f}};
  f32x4 accB[4] = {{0.f, 0.f, 0.f, 0.f}, {0.f, 0.f, 0.f, 0.f},
                   {0.f, 0.f, 0.f, 0.f}, {0.f, 0.f, 0.f, 0.f}};
  const ushort* Ap = Hb + (size_t)(row0 + mh * 16 + l15) * 128 + quad * 8;
#pragma unroll
  for (int k0 = 0; k0 < 128; k0 += 32) {
    bf16x8 af = *(const bf16x8*)(Ap + k0);
#pragma unroll
    for (int t = 0; t < 4; ++t) {
      int bn = col0 + nh * 64 + t * 16 + l15;
      const ushort* Brow = W1t + (size_t)bn * 256 + k0 + quad * 8;
      bf16x8 bfa = *(const bf16x8*)(Brow);
      bf16x8 bfb = *(const bf16x8*)(Brow + 128);
      accA[t] = __builtin_amdgcn_mfma_f32_16x16x32_bf16(af, bfa, accA[t], 0, 0, 0);
      accB[t] = __builtin_amdgcn_mfma_f32_16x16x32_bf16(af, bfb, accB[t], 0, 0, 0);
    }
  }
#pragma unroll
  for (int pass = 0; pass < 2; ++pass) {
    if (pass) __syncthreads();          // previous pass's readers done
#pragma unroll
    for (int t = 0; t < 4; ++t) {
      int lc = nh * 64 + t * 16 + l15;
      float bs = pass ? 0.f : b1[col0 + lc];
      f32x4 av = pass ? accB[t] : accA[t];
#pragma unroll
      for (int r = 0; r < 4; ++r)
        lds[mh * 16 + quad * 4 + r][lc] = av[r] + bs;
    }
    __syncthreads();
    ushort* C = pass ? Pb : Pa;
    const int r = tid >> 3, c0 = (tid & 7) * 16;
    ushort* Cp = C + (size_t)(row0 + r) * 512 + col0 + c0;
#pragma unroll
    for (int k = 0; k < 4; ++k) {
      f32x4 v = *(const f32x4*)&lds[r][c0 + k * 4];
      ushort4 o;
      o.x = f2bf(v[0]); o.y = f2bf(v[1]); o.z = f2bf(v[2]); o.w = f2bf(v[3]);
      *(ushort4*)(Cp + k * 4) = o;
    }
  }
}

// ---------------- edge MLP layer 2: one full wave per dst node --------------
// v6 = pipelined wave-per-node (coalesced full-row reads, butterfly) with
// eclamp speculation. [round 8: 51.5 us, FETCH at the 8-XCD compulsory floor]
__global__ __launch_bounds__(256) void edge_pe_csr(
    const ushort* __restrict__ Pa, const ushort* __restrict__ Pb,
    const int* __restrict__ gsrc, const int* __restrict__ rs,
    const float* __restrict__ W2, const float* __restrict__ b2,
    float* __restrict__ pe) {
  const int lane = threadIdx.x & 63;
  const int n = blockIdx.x * 4 + (threadIdx.x >> 6);
  const int e0 = rs[n];
  const int deg = rs[n + 1] - e0;
  if (deg <= 0) return;
  const int hi = e0 + deg - 1;
  float w[8], pb[8];
  {
    const float4* w2v = (const float4*)(W2 + lane * 8);
    float4 t0 = w2v[0], t1 = w2v[1];
    w[0] = t0.x; w[1] = t0.y; w[2] = t0.z; w[3] = t0.w;
    w[4] = t1.x; w[5] = t1.y; w[6] = t1.z; w[7] = t1.w;
    uint4 b = ((const uint4*)(Pb + (size_t)n * 512))[lane];
    pb[0] = bflo(b.x); pb[1] = bfhi(b.x); pb[2] = bflo(b.y); pb[3] = bfhi(b.y);
    pb[4] = bflo(b.z); pb[5] = bfhi(b.z); pb[6] = bflo(b.w); pb[7] = bfhi(b.w);
  }
  const float b2v = b2[0];
  const uint4* Par = (const uint4*)Pa;

  int i0 = gsrc[eclamp(e0 + 0, hi)];
  int i1 = gsrc[eclamp(e0 + 1, hi)];
  int i2 = gsrc[eclamp(e0 + 2, hi)];
  int i3 = gsrc[eclamp(e0 + 3, hi)];
  uint4 F0 = Par[(size_t)i0 * 64 + lane];
  uint4 F1 = Par[(size_t)i1 * 64 + lane];
  uint4 F2 = Par[(size_t)i2 * 64 + lane];
  uint4 F3 = Par[(size_t)i3 * 64 + lane];
  int G0 = gsrc[eclamp(e0 + 4, hi)];
  int G1 = gsrc[eclamp(e0 + 5, hi)];
  int G2 = gsrc[eclamp(e0 + 6, hi)];
  int G3 = gsrc[eclamp(e0 + 7, hi)];

#define PE_STEP(F, G, J)                                                      \
  {                                                                           \
    if ((J) < deg) {                                                          \
      float pa[8] = {bflo(F.x), bfhi(F.x), bflo(F.y), bfhi(F.y),              \
                     bflo(F.z), bfhi(F.z), bflo(F.w), bfhi(F.w)};             \
      float acc = 0.f;                                                        \
      _Pragma("unroll")                                                       \
      for (int jj = 0; jj < 8; ++jj) acc += fmaxf(pa[jj] + pb[jj], 0.f) * w[jj]; \
      _Pragma("unroll")                                                       \
      for (int off = 32; off; off >>= 1) acc += __shfl_xor(acc, off);         \
      if (lane == 0) pe[e0 + (J)] = acc + b2v;                                \
    }                                                                         \
    F = Par[(size_t)G * 64 + lane];                                           \
    G = gsrc[eclamp(e0 + (J) + 8, hi)];                                       \
  }

  for (int j = 0; j < deg; j += 4) {
    PE_STEP(F0, G0, j);
    PE_STEP(F1, G1, j + 1);
    PE_STEP(F2, G2, j + 2);
    PE_STEP(F3, G3, j + 3);
  }
#undef PE_STEP
}

// ---------------- pe statistics (sum, sumsq, min, max) ----------------------
__global__ __launch_bounds__(256) void pe_stats(const float* __restrict__ pe,
                                                float* __restrict__ scal) {
  __shared__ float r1[256], r2[256], r3[256], r4[256];
  int tid = threadIdx.x;
  float s = 0.f, q = 0.f, mn = 3.0e38f, mx = -3.0e38f;
  for (int i = blockIdx.x * 256 + tid; i < EE; i += gridDim.x * 256) {
    float v = pe[i];
    s += v; q = fmaf(v, v, q);
    mn = fminf(mn, v); mx = fmaxf(mx, v);
  }
  r1[tid] = s; r2[tid] = q; r3[tid] = mn; r4[tid] = mx;
  __syncthreads();
  for (int k = 128; k > 0; k >>= 1) {
    if (tid < k) {
      r1[tid] += r1[tid + k];
      r2[tid] += r2[tid + k];
      r3[tid] = fminf(r3[tid], r3[tid + k]);
      r4[tid] = fmaxf(r4[tid], r4[tid + k]);
    }
    __syncthreads();
  }
  if (tid == 0) {
    unsafeAtomicAdd(&scal[0], r1[0]);
    unsafeAtomicAdd(&scal[1], r2[0]);
    atomicMin((unsigned*)scal + 2, ordf(r3[0]));
    atomicMax((unsigned*)scal + 3, ordf(r4[0]));
  }
}

// ---------------- delta + histogram (CSR order; u gathered via eidx) --------
__global__ __launch_bounds__(256) void edge_delta_hist(
    const float* __restrict__ pe, const float* __restrict__ u,
    const int* __restrict__ eidx, float* __restrict__ delta,
    float* __restrict__ hist, const float* __restrict__ scal) {
  __shared__ float cnt_s[NBINS], sum_s[NBINS];
  for (int b = threadIdx.x; b < NBINS; b += 256) { cnt_s[b] = 0.f; sum_s[b] = 0.f; }
  float sum = scal[0], ssq = scal[1];
  float mn = unordf(((const unsigned*)scal)[2]);
  float mx = unordf(((const unsigned*)scal)[3]);
  float mu = sum / (float)EE;
  float var = (ssq - sum * sum / (float)EE) / (float)(EE - 1);
  float istd = rsqrtf(fmaxf(var, 1e-30f));
  float shift = (mn - mu) * istd + (mx - mu) * istd;
  __syncthreads();
  for (int i = blockIdx.x * 256 + threadIdx.x; i < EE; i += gridDim.x * 256) {
    float uu = u[eidx[i]];
    float atts = (pe[i] - mu) * istd;
    float g = -logf(-logf(uu + EPSF) + EPSF);
    float dl = 2.0f * (atts + g) - shift;
    delta[i] = dl;
    float dcl = fminf(fmaxf(dl, -HRANGE), HRANGE * 0.9999f);
    int b = (int)((dcl + HRANGE) * ((float)NBINS / (2.0f * HRANGE)));
    b = min(max(b, 0), NBINS - 1);
    atomicAdd(&cnt_s[b], 1.0f);
    atomicAdd(&sum_s[b], dcl);
  }
  __syncthreads();
  for (int b = threadIdx.x; b < NBINS; b += 256) {
    float c = cnt_s[b];
    if (c != 0.f) {
      unsafeAtomicAdd(&hist[b], c);
      unsafeAtomicAdd(&hist[NBINS + b], sum_s[b]);
    }
  }
}

// ---------------- Sinkhorn recursion: 256 threads, LDS state ----------------
// v2 (round 13): the old single-wave version cost 62.7us — 30 serial
// iterations x (32 expf + 32 precise div)/lane with cnt[]/mean[] spilled to
// SCRATCH (VGPR_Count=44 < the 64 regs needed). Fixes:
//  - exp hoist: exp(-(mean+S)) = exp(-mean)*exp(-S); em[] precomputed once ->
//    ONE expf per iteration (math-identical to ~2ulp).
//  - cnt/em in LDS (16KB), not scratch.
//  - 256 threads, 8 bins/lane; cross-wave reduce via 4-slot LDS + barrier.
//  - branchless: cnt==0 bins have em=1 and contribute 0/(1+t)=0.
// S drifts ~1e-6 rel vs old formulation — invisible in bf16 out (thr 7.0).
__global__ __launch_bounds__(256) void sinkhorn_iter(const float* __restrict__ hist,
                                                     float* __restrict__ scal) {
  __shared__ float cntS[NBINS];
  __shared__ float emS[NBINS];
  __shared__ float red[4];
  const int tid = threadIdx.x;
  const int lane = tid & 63, wv = tid >> 6;
  for (int b = tid; b < NBINS; b += 256) {
    float c = hist[b];
    float m = (c > 0.f) ? hist[NBINS + b] / c : 0.f;
    cntS[b] = c;
    emS[b] = expf(-m);
  }
  __syncthreads();
  const float LRD = -1.0986122886681098f;
  float S = 0.f, Zfin = 0.f;
  for (int it = 0; it < 30; ++it) {
    const float t = expf(-S);
    float p = 0.f;
#pragma unroll
    for (int j = 0; j < 8; ++j) {
      int b = j * 256 + tid;
      p += cntS[b] / (1.f + emS[b] * t);
    }
#pragma unroll
    for (int off = 32; off; off >>= 1) p += __shfl_xor(p, off);
    if (lane == 0) red[wv] = p;
    __syncthreads();
    p = (red[0] + red[1]) + (red[2] + red[3]);
    if (it < 29)
      S += logf(fmaxf((float)EE - p, 1.0f)) - logf(p) + LRD;
    else
      Zfin = p;
    __syncthreads();   // red[] consumed before next iteration's writes
  }
  if (tid == 0) {
    scal[8] = S;
    scal[9] = ((float)EE * 0.25f) / Zfin;
  }
}

// ---------------- T_i (CSR order) -------------------------------------------
__global__ void compute_T(const float* __restrict__ delta,
                          const float* __restrict__ scal,
                          float* __restrict__ Ta) {
  int i = blockIdx.x * 256 + threadIdx.x;
  if (i >= EE) return;
  float S = scal[8], sc = scal[9];
  Ta[i] = sc / (1.f + expf(-(delta[i] + S)));
}

// ---------------- mean pooling (4 independent partials) + head --------------
__global__ __launch_bounds__(128) void col_mean(const ushort* __restrict__ Hc,
                                                float* __restrict__ rep) {
  int c = threadIdx.x;
  const int g = gridDim.x;
  float p0 = 0.f, p1 = 0.f, p2 = 0.f, p3 = 0.f;
  int n = blockIdx.x;
  for (; n + 3 * g < NN; n += 4 * g) {
    p0 += bf2f(Hc[(size_t)n * 128 + c]);
    p1 += bf2f(Hc[(size_t)(n + g) * 128 + c]);
    p2 += bf2f(Hc[(size_t)(n + 2 * g) * 128 + c]);
    p3 += bf2f(Hc[(size_t)(n + 3 * g) * 128 + c]);
  }
  for (; n < NN; n += g) p0 += bf2f(Hc[(size_t)n * 128 + c]);
  unsafeAtomicAdd(&rep[c], (p0 + p1) + (p2 + p3));
}

__global__ __launch_bounds__(128) void head_kernel(const float* __restrict__ repsum,
                                                   const float* __restrict__ hW,
                                                   const float* __restrict__ hb,
                                                   float* __restrict__ out) {
  __shared__ float rep[128];
  int tid = threadIdx.x;
  if (tid < 128) rep[tid] = repsum[tid] * (1.0f / (float)NN);
  __syncthreads();
  if (tid < 10) {
    float a = hb[tid];
#pragma unroll
    for (int c = 0; c < 128; c++) a = fmaf(rep[c], hW[c * 10 + tid], a);
    out[tid] = a;
  }
}

// ---------------- launch ----------------------------------------------------
extern "C" void kernel_launch(void* const* d_in, const int* in_sizes, int n_in,
                              void* d_out, int out_size, void* d_ws, size_t ws_size,
                              hipStream_t stream) {
  const float* x      = (const float*)d_in[0];
  const int*   ei     = (const int*)d_in[1];
  const float* u      = (const float*)d_in[2];
  const float* enc_W0 = (const float*)d_in[3];
  const float* enc_b0 = (const float*)d_in[4];
  const float* enc_W  = (const float*)d_in[5];
  const float* enc_b  = (const float*)d_in[6];
  const float* ea_W1  = (const float*)d_in[7];
  const float* ea_b1  = (const float*)d_in[8];
  const float* ea_W2  = (const float*)d_in[9];
  const float* ea_b2  = (const float*)d_in[10];
  const float* cls_W0 = (const float*)d_in[11];
  const float* cls_b0 = (const float*)d_in[12];
  const float* cls_W  = (const float*)d_in[13];
  const float* cls_b  = (const float*)d_in[14];
  const float* head_W = (const float*)d_in[15];
  const float* head_b = (const float*)d_in[16];
  const int* src  = ei;
  const int* dstp = ei + EE;

  float* wsF = (float*)d_ws;
  int*   wsI = (int*)d_ws;
  int* deg  = wsI + OFF_DEG;
  int* rs   = wsI + OFF_RS;
  int* cur  = wsI + OFF_CUR;
  int* eix  = wsI + OFF_EIX;
  int* gsrc = wsI + OFF_GSRC;
  ushort* B0 = (ushort*)(wsF + OFF_B0);
  ushort* B1 = (ushort*)(wsF + OFF_B1);
  ushort* Pa = (ushort*)(wsF + OFF_PA);
  ushort* Pb = (ushort*)(wsF + OFF_PB);
  float* pe   = wsF + OFF_PE;
  float* dl   = wsF + OFF_DL;
  float* Ta   = wsF + OFF_TT;
  float* hist = wsF + OFF_HIST;
  float* scal = wsF + OFF_SCAL;
  float* rep  = wsF + OFF_REP;
  ushort* Wt  = (ushort*)(wsF + OFF_WT);
  float* out = (float*)d_out;

  init_ws<<<(NN + 255) / 256, 256, 0, stream>>>(deg, cur, hist, scal, rep);
  count_deg<<<(EE + 255) / 256, 256, 0, stream>>>(dstp, deg);
  scan_deg<<<1, 1024, 0, stream>>>(deg, rs);
  fill_csr<<<(EE + 255) / 256, 256, 0, stream>>>(src, dstp, rs, cur, eix, gsrc);
  transpose_all<<<1088, 256, 0, stream>>>(enc_W0, enc_W, cls_W0, cls_W, ea_W1, Wt);

  const int GB = NN / 16;  // 1250 (16 nodes per block) — the 517-521us config

  // encoder GIN stack (att = 1)
  fused_layer64<false><<<GB, 256, 0, stream>>>(x, B0, gsrc, rs, nullptr, Wt + WT_ENC0, enc_b0);
  {
    ushort* in = B0; ushort* outb = B1;
    for (int l = 0; l < 4; l++) {
      fused_layer128<false><<<GB, 256, 0, stream>>>(in, outb, gsrc, rs, nullptr,
                                                    Wt + WT_ENC + (size_t)l * 16384,
                                                    enc_b + (size_t)l * 128);
      ushort* t = in; in = outb; outb = t;
    }
  }
  // encoder output in B0

  gemm_papb<<<dim3(4, NN / 32), 256, 0, stream>>>(B0, Wt + WT_EA1, ea_b1, Pa, Pb);
  edge_pe_csr<<<NN / 4, 256, 0, stream>>>(Pa, Pb, gsrc, rs, ea_W2, ea_b2, pe);

  pe_stats<<<512, 256, 0, stream>>>(pe, scal);
  edge_delta_hist<<<128, 256, 0, stream>>>(pe, u, eix, dl, hist, scal);
  sinkhorn_iter<<<1, 256, 0, stream>>>(hist, scal);
  compute_T<<<(EE + 255) / 256, 256, 0, stream>>>(dl, scal, Ta);

  // classifier GIN stack (att = T, CSR-ordered)
  fused_layer64<true><<<GB, 256, 0, stream>>>(x, B0, gsrc, rs, Ta, Wt + WT_CLS0, cls_b0);
  {
    ushort* in = B0; ushort* outb = B1;
    for (int l = 0; l < 4; l++) {
      fused_layer128<true><<<GB, 256, 0, stream>>>(in, outb, gsrc, rs, Ta,
                                                   Wt + WT_CLS + (size_t)l * 16384,
                                                   cls_b + (size_t)l * 128);
      ushort* t = in; in = outb; outb = t;
    }
  }

  col_mean<<<256, 128, 0, stream>>>(B0, rep);
  head_kernel<<<1, 128, 0, stream>>>(rep, head_W, head_b, out);
}